// Round 18
// baseline (366.648 us; speedup 1.0000x reference)
//
#include <hip/hip_runtime.h>

#define NN 100000
#define EE 1200000
#define ALPHA_C 0.2f
#define EPS_C 1e-5f

typedef __attribute__((ext_vector_type(8))) short short8;
typedef __attribute__((ext_vector_type(4))) float f32x4;
#define MFMA __builtin_amdgcn_mfma_f32_16x16x32_bf16

#define PITCH 72  // LDS tile pitch (ushorts): 144B rows, 16B-aligned frags

// ---------------- bf16 helpers ----------------

__device__ __forceinline__ ushort f2bf(float f) {
  unsigned u = __float_as_uint(f);
  unsigned r = (u + 0x7FFFu + ((u >> 16) & 1u)) >> 16;
  return (ushort)r;
}
__device__ __forceinline__ float bf2f(ushort h) { return __uint_as_float((unsigned)h << 16); }

__device__ __forceinline__ float ftanh(float x) {  // validated (rounds 8/11/12/16 pass)
  float ax = fabsf(x);
  float e = __expf(2.f * ax);
  float t = 1.f - 2.f / (e + 1.f);
  return copysignf(t, x);
}

// ---------------- CSR build ----------------

__global__ __launch_bounds__(256) void k_countrank(const int* __restrict__ dstv,
                                                   int* __restrict__ deg, int* __restrict__ rank) {
  int e = blockIdx.x * 256 + threadIdx.x;
  if (e < EE) rank[e] = atomicAdd(&deg[dstv[e]], 1);
}

__global__ __launch_bounds__(256) void k_scan1(const int* __restrict__ deg, int* __restrict__ rowp,
                                               int* __restrict__ bsum, float* __restrict__ dinv) {
  __shared__ int s[256];
  int t = threadIdx.x;
  int i = blockIdx.x * 256 + t;
  int v = (i < NN) ? deg[i] : 0;
  if (i < NN) dinv[i] = rsqrtf((float)v + 1.0f);  // +1 self-loop
  s[t] = v;
  __syncthreads();
  for (int off = 1; off < 256; off <<= 1) {
    int add = (t >= off) ? s[t - off] : 0;
    __syncthreads();
    s[t] += add;
    __syncthreads();
  }
  if (i < NN) rowp[i] = s[t] - v;
  if (t == 255) bsum[blockIdx.x] = s[255];
}

__global__ __launch_bounds__(512) void k_scan2(int* __restrict__ bsum, int* __restrict__ rowp, int nb) {
  __shared__ int s[512];
  int t = threadIdx.x;
  int v = (t < nb) ? bsum[t] : 0;
  s[t] = v;
  __syncthreads();
  for (int off = 1; off < 512; off <<= 1) {
    int add = (t >= off) ? s[t - off] : 0;
    __syncthreads();
    s[t] += add;
    __syncthreads();
  }
  if (t < nb) bsum[t] = s[t] - v;
  if (t == 0) rowp[NN] = EE;
}

__global__ __launch_bounds__(256) void k_scan3(int* __restrict__ rowp, const int* __restrict__ bsum) {
  int i = blockIdx.x * 256 + threadIdx.x;
  if (i < NN) rowp[i] += bsum[blockIdx.x];
}

__global__ __launch_bounds__(256) void k_fill(const int* __restrict__ srcv, const int* __restrict__ dstv,
                                              const int* __restrict__ rowp, const int* __restrict__ rank,
                                              int* __restrict__ col) {
  int e = blockIdx.x * 256 + threadIdx.x;
  if (e < EE) col[rowp[dstv[e]] + rank[e]] = srcv[e];
}

// ---------------- SpMM ----------------

__global__ __launch_bounds__(256) void k_prescale(const float* __restrict__ feat,
                                                  const float* __restrict__ dinv,
                                                  float* __restrict__ xs) {
  int idx = blockIdx.x * 256 + threadIdx.x;
  if (idx < NN * 16) {
    float4 v = ((const float4*)feat)[idx];
    float d = dinv[idx >> 4];
    v.x *= d; v.y *= d; v.z *= d; v.w *= d;
    ((float4*)xs)[idx] = v;
  }
}

// out: packed bf16 hi||lo A-fragment layout, 128 ushorts/node ([64 hi][64 lo])
// 8-way unrolled gather (latency-bound: more outstanding loads per wave)
__global__ __launch_bounds__(256) void k_spmm(const float4* __restrict__ xs4, const float* __restrict__ dinv,
                                              const int* __restrict__ rowp, const int* __restrict__ col,
                                              ushort* __restrict__ outP) {
  int node = blockIdx.x * 16 + (threadIdx.x >> 4);
  int q = threadIdx.x & 15;
  if (node >= NN) return;
  int s = rowp[node], e = rowp[node + 1];
  float4 a0 = {0.f, 0.f, 0.f, 0.f}, a1 = a0, a2 = a0, a3 = a0;
  float4 a4 = a0, a5 = a0, a6 = a0, a7 = a0;
  int j = s;
  for (; j + 8 <= e; j += 8) {
    int c0 = col[j],     c1 = col[j + 1], c2 = col[j + 2], c3 = col[j + 3];
    int c4 = col[j + 4], c5 = col[j + 5], c6 = col[j + 6], c7 = col[j + 7];
    float4 v0 = xs4[c0 * 16 + q];
    float4 v1 = xs4[c1 * 16 + q];
    float4 v2 = xs4[c2 * 16 + q];
    float4 v3 = xs4[c3 * 16 + q];
    float4 v4 = xs4[c4 * 16 + q];
    float4 v5 = xs4[c5 * 16 + q];
    float4 v6 = xs4[c6 * 16 + q];
    float4 v7 = xs4[c7 * 16 + q];
    a0 += v0; a1 += v1; a2 += v2; a3 += v3;
    a4 += v4; a5 += v5; a6 += v6; a7 += v7;
  }
  for (; j + 4 <= e; j += 4) {
    int c0 = col[j], c1 = col[j + 1], c2 = col[j + 2], c3 = col[j + 3];
    float4 v0 = xs4[c0 * 16 + q];
    float4 v1 = xs4[c1 * 16 + q];
    float4 v2 = xs4[c2 * 16 + q];
    float4 v3 = xs4[c3 * 16 + q];
    a0 += v0; a1 += v1; a2 += v2; a3 += v3;
  }
  for (; j < e; ++j) a0 += xs4[col[j] * 16 + q];
  float4 sv = xs4[node * 16 + q];
  float d = dinv[node];
  a0 += a4; a1 += a5; a2 += a6; a3 += a7;
  float4 o;
  o.x = d * (a0.x + a1.x + a2.x + a3.x + sv.x);
  o.y = d * (a0.y + a1.y + a2.y + a3.y + sv.y);
  o.z = d * (a0.z + a1.z + a2.z + a3.z + sv.z);
  o.w = d * (a0.w + a1.w + a2.w + a3.w + sv.w);
  ushort h0 = f2bf(o.x), h1 = f2bf(o.y), h2 = f2bf(o.z), h3 = f2bf(o.w);
  ushort l0 = f2bf(o.x - bf2f(h0)), l1 = f2bf(o.y - bf2f(h1)),
         l2 = f2bf(o.z - bf2f(h2)), l3 = f2bf(o.w - bf2f(h3));
  ushort* p = outP + (size_t)node * 128 + 4 * q;
  *(ushort4*)(p) = make_ushort4(h0, h1, h2, h3);
  *(ushort4*)(p + 64) = make_ushort4(l0, l1, l2, l3);
}

// ---------------- weight pre-pack (B-fragment order, hi||lo bf16) + deg zero ----------

__global__ __launch_bounds__(256) void k_packz(const float* __restrict__ Wh, const float* __restrict__ Wx,
                                               const float* __restrict__ ff1w, const float* __restrict__ ff2w,
                                               const float* __restrict__ c1w, const float* __restrict__ c2w,
                                               ushort* __restrict__ wpk, int* __restrict__ deg) {
  int i = blockIdx.x * 256 + threadIdx.x;
  if (i < NN) deg[i] = 0;
  int id = blockIdx.x;
  if (id >= 22) return;
  const float* src;
  int ncol = 64, vcol = 64;
  if (id < 8) src = Wx + id * 4096;
  else if (id < 16) src = Wh + (id - 8) * 4096;
  else if (id < 18) src = ff1w + (id - 16) * 4096;
  else if (id < 20) src = ff2w + (id - 18) * 4096;
  else if (id == 20) src = c1w;
  else { src = c2w; ncol = 40; vcol = 40; }
  ushort* dst = wpk + (size_t)id * 8192;
  for (int p = threadIdx.x; p < 512; p += 256) {
    int f = p >> 6, l = p & 63;
    int kh = f & 1, tc = f >> 1;
    int r0 = 32 * kh + 8 * (l >> 4), c = 16 * tc + (l & 15);
#pragma unroll
    for (int j = 0; j < 8; ++j) {
      float v = (c < vcol) ? src[(r0 + j) * ncol + c] : 0.f;
      ushort h = f2bf(v);
      dst[f * 512 + l * 8 + j] = h;
      dst[4096 + f * 512 + l * 8 + j] = f2bf(v - bf2f(h));
    }
  }
}

// ---------------- dense helpers ----------------

__device__ __forceinline__ float red16(float v) {
  v += __shfl_xor(v, 1);
  v += __shfl_xor(v, 2);
  v += __shfl_xor(v, 4);
  v += __shfl_xor(v, 8);
  return v;
}

__device__ __forceinline__ void stageB(const ushort* __restrict__ wp, ushort* __restrict__ bsta, int t) {
#pragma unroll
  for (int u = 0; u < 4; ++u) {
    int o = (u * 256 + t) * 8;
    *(short8*)(bsta + o) = *(const short8*)(wp + o);
  }
}

template <int NT>
__device__ __forceinline__ void mm_mfma_l(short8 a0h, short8 a1h, short8 a0l, short8 a1l,
                                          const ushort* __restrict__ bsta, int l, f32x4* C) {
#pragma unroll
  for (int tc = 0; tc < NT; ++tc) {
#pragma unroll
    for (int kh = 0; kh < 2; ++kh) {
      const short8 bh = *(const short8*)(bsta + (tc * 2 + kh) * 512 + l * 8);
      const short8 bl = *(const short8*)(bsta + 4096 + (tc * 2 + kh) * 512 + l * 8);
      const short8 ah = kh ? a1h : a0h;
      const short8 alo = kh ? a1l : a0l;
      C[tc] = MFMA(ah, bh, C[tc], 0, 0, 0);
      C[tc] = MFMA(ah, bl, C[tc], 0, 0, 0);
      C[tc] = MFMA(alo, bh, C[tc], 0, 0, 0);
    }
  }
}

__device__ __forceinline__ void ln_frag(float v[4][4]) {
#pragma unroll
  for (int r = 0; r < 4; ++r) {
    float s = v[0][r] + v[1][r] + v[2][r] + v[3][r];
    s = red16(s);
    float mu = s * 0.015625f;
    float q = 0.f;
#pragma unroll
    for (int tc = 0; tc < 4; ++tc) { float d = v[tc][r] - mu; q = fmaf(d, d, q); }
    q = red16(q);
    float inv = rsqrtf(q * 0.015625f + EPS_C);
#pragma unroll
    for (int tc = 0; tc < 4; ++tc) v[tc][r] = (v[tc][r] - mu) * inv;
  }
}

// ---------------- fused per-layer kernel (r16 proven structure) ----------------
// 64 nodes/block, 4 waves; dual-buffer head staging (bs0=Wx_k, bs1=Wh_k), 2 barriers/head.
// Gate computed in-loop from MFMA outputs (proven). Head loop statically unrolled.
// C/D frag: row = 16w + 4*(l>>4) + r, col = (l&15) + 16*tc.

template <int HAS_H, int WSC, int DO_CLF>
__global__ __launch_bounds__(256) void k_layer(
    const ushort* __restrict__ aggXP, const ushort* __restrict__ aggHP,
    const float* __restrict__ h_in, float* __restrict__ h_out,
    float* __restrict__ hs_out, const float* __restrict__ dinv,
    const ushort* __restrict__ wxp, const ushort* __restrict__ whp,
    const float* __restrict__ bxl, const float* __restrict__ bhl,
    const float* __restrict__ gfw, const float* __restrict__ gfb,
    const float* __restrict__ guw, const float* __restrict__ gub,
    const ushort* __restrict__ ff1p, const float* __restrict__ ff1b,
    const ushort* __restrict__ ff2p, const float* __restrict__ ff2b,
    const ushort* __restrict__ c1p, const float* __restrict__ c1b,
    const ushort* __restrict__ c2p, const float* __restrict__ c2b,
    float* __restrict__ outv) {
  __shared__ __align__(16) ushort th[64 * PITCH], tl[64 * PITCH];
  __shared__ __align__(16) ushort bs0[8192], bs1[8192];
  const int t = threadIdx.x, blk = blockIdx.x;
  const int w = t >> 6, l = t & 63, lg = l >> 4, lr = l & 15;
  const int abase = (16 * w + lr) * PITCH + 8 * lg;
  const int arow = blk * 64 + 16 * w + lr;
  const int arowc = arow < NN ? arow : NN - 1;

  const ushort* axp = aggXP + (size_t)arowc * 128 + 8 * lg;
  short8 xa0h = *(const short8*)(axp);
  short8 xa1h = *(const short8*)(axp + 32);
  short8 xa0l = *(const short8*)(axp + 64);
  short8 xa1l = *(const short8*)(axp + 96);
  short8 ha0h = (short8)0, ha1h = (short8)0, ha0l = (short8)0, ha1l = (short8)0;
  if (HAS_H) {
    const ushort* ahp = aggHP + (size_t)arowc * 128 + 8 * lg;
    ha0h = *(const short8*)(ahp);
    ha1h = *(const short8*)(ahp + 32);
    ha0l = *(const short8*)(ahp + 64);
    ha1l = *(const short8*)(ahp + 96);
  }

  float gfhw[4], gfxw[4], guhw[4], guxw[4];
#pragma unroll
  for (int tc = 0; tc < 4; ++tc) {
    gfhw[tc] = gfw[lr + 16 * tc]; gfxw[tc] = gfw[64 + lr + 16 * tc];
    guhw[tc] = guw[lr + 16 * tc]; guxw[tc] = guw[64 + lr + 16 * tc];
  }
  const float gfb0 = gfb[0], gub0 = gub[0];

  float acc[4][4];
#pragma unroll
  for (int tc = 0; tc < 4; ++tc)
#pragma unroll
    for (int r = 0; r < 4; ++r) acc[tc][r] = 0.f;

  // ---- head loop: dual-buffer stage, 2 barriers per head (statically unrolled) ----
#pragma unroll
  for (int k = 0; k < 4; ++k) {
    f32x4 cx[4], ch[4];
#pragma unroll
    for (int tc = 0; tc < 4; ++tc) { cx[tc] = (f32x4)0.f; ch[tc] = (f32x4)0.f; }
    __syncthreads();  // prior readers of bs0/bs1 done
    stageB(wxp + k * 8192, bs0, t);
    if (HAS_H) stageB(whp + k * 8192, bs1, t);
    __syncthreads();  // staged
    mm_mfma_l<4>(xa0h, xa1h, xa0l, xa1l, bs0, l, cx);
    if (HAS_H) mm_mfma_l<4>(ha0h, ha1h, ha0l, ha1l, bs1, l, ch);

    float Cx[4][4], Ch[4][4];
#pragma unroll
    for (int tc = 0; tc < 4; ++tc) {
      float bxv = bxl[k * 64 + lr + 16 * tc];
      float bhv = bhl[k * 64 + lr + 16 * tc];
#pragma unroll
      for (int r = 0; r < 4; ++r) {
        Cx[tc][r] = cx[tc][r] + bxv;
        Ch[tc][r] = (HAS_H ? ch[tc][r] : 0.f) + bhv;
      }
    }
#pragma unroll
    for (int r = 0; r < 4; ++r) {
      float pf = 0.f, pu = 0.f;
#pragma unroll
      for (int tc = 0; tc < 4; ++tc) {
        pf = fmaf(Ch[tc][r], gfhw[tc], pf); pf = fmaf(Cx[tc][r], gfxw[tc], pf);
        pu = fmaf(Ch[tc][r], guhw[tc], pu); pu = fmaf(Cx[tc][r], guxw[tc], pu);
      }
      pf = red16(pf); pu = red16(pu);
      float fv = ALPHA_C * ftanh(pf + gfb0);
      float uv = ALPHA_C * ftanh(pu + gub0);
#pragma unroll
      for (int tc = 0; tc < 4; ++tc)
        acc[tc][r] += (1.f + fv) * Ch[tc][r] + (1.f + uv) * Cx[tc][r];
    }
  }

  // hmid = acc/4 + h_in ; LN
  float hmid[4][4];
#pragma unroll
  for (int tc = 0; tc < 4; ++tc)
#pragma unroll
    for (int r = 0; r < 4; ++r) {
      float hv = 0.f;
      if (HAS_H) {
        int gn = blk * 64 + 16 * w + 4 * lg + r;
        if (gn > NN - 1) gn = NN - 1;
        hv = h_in[gn * 64 + lr + 16 * tc];
      }
      hmid[tc][r] = fmaf(acc[tc][r], 0.25f, hv);
    }
  ln_frag(hmid);

  __syncthreads();  // all waves past last head phase (bs0/bs1 reads retired)
#pragma unroll
  for (int tc = 0; tc < 4; ++tc)
#pragma unroll
    for (int r = 0; r < 4; ++r) {
      int o = (16 * w + 4 * lg + r) * PITCH + lr + 16 * tc;
      ushort h = f2bf(hmid[tc][r]);
      th[o] = h;
      tl[o] = f2bf(hmid[tc][r] - bf2f(h));
    }
  __syncthreads();
  short8 m0h = *(const short8*)(th + abase);
  short8 m1h = *(const short8*)(th + abase + 32);
  short8 m0l = *(const short8*)(tl + abase);
  short8 m1l = *(const short8*)(tl + abase + 32);

  f32x4 f1[4];
#pragma unroll
  for (int tc = 0; tc < 4; ++tc) f1[tc] = (f32x4)0.f;
  __syncthreads();  // m-frag reads done (held in regs) before bs0 restage
  stageB(ff1p, bs0, t);
  __syncthreads();
  mm_mfma_l<4>(m0h, m1h, m0l, m1l, bs0, l, f1);
#pragma unroll
  for (int tc = 0; tc < 4; ++tc) {
    float bv = ff1b[lr + 16 * tc];
#pragma unroll
    for (int r = 0; r < 4; ++r) {
      float v = fmaxf(f1[tc][r] + bv, 0.f);
      int o = (16 * w + 4 * lg + r) * PITCH + lr + 16 * tc;
      ushort h = f2bf(v);
      th[o] = h;
      tl[o] = f2bf(v - bf2f(h));
    }
  }
  __syncthreads();
  short8 g0h = *(const short8*)(th + abase);
  short8 g1h = *(const short8*)(th + abase + 32);
  short8 g0l = *(const short8*)(tl + abase);
  short8 g1l = *(const short8*)(tl + abase + 32);

  f32x4 f2[4];
#pragma unroll
  for (int tc = 0; tc < 4; ++tc) f2[tc] = (f32x4)0.f;
  __syncthreads();
  stageB(ff2p, bs0, t);
  __syncthreads();
  mm_mfma_l<4>(g0h, g1h, g0l, g1l, bs0, l, f2);
  float F2[4][4];
#pragma unroll
  for (int tc = 0; tc < 4; ++tc) {
    float bv = ff2b[lr + 16 * tc];
#pragma unroll
    for (int r = 0; r < 4; ++r) F2[tc][r] = f2[tc][r] + bv + hmid[tc][r];
  }
  ln_frag(F2);

  if (!DO_CLF) {
#pragma unroll
    for (int r = 0; r < 4; ++r) {
      int gn = blk * 64 + 16 * w + 4 * lg + r;
      if (gn < NN) {
        float dv = WSC ? dinv[gn] : 0.f;
#pragma unroll
        for (int tc = 0; tc < 4; ++tc) {
          h_out[gn * 64 + lr + 16 * tc] = F2[tc][r];
          if (WSC) hs_out[gn * 64 + lr + 16 * tc] = F2[tc][r] * dv;
        }
      }
    }
    return;
  }

  // ===== classifier tail =====
  __syncthreads();  // all waves past FF2 mm (bs0 + tile reads retired)
#pragma unroll
  for (int tc = 0; tc < 4; ++tc)
#pragma unroll
    for (int r = 0; r < 4; ++r) {
      int o = (16 * w + 4 * lg + r) * PITCH + lr + 16 * tc;
      ushort h = f2bf(F2[tc][r]);
      th[o] = h;
      tl[o] = f2bf(F2[tc][r] - bf2f(h));
    }
  stageB(c1p, bs0, t);
  __syncthreads();
  short8 p0h = *(const short8*)(th + abase);
  short8 p1h = *(const short8*)(th + abase + 32);
  short8 p0l = *(const short8*)(tl + abase);
  short8 p1l = *(const short8*)(tl + abase + 32);

  f32x4 c1[4];
#pragma unroll
  for (int tc = 0; tc < 4; ++tc) c1[tc] = (f32x4)0.f;
  mm_mfma_l<4>(p0h, p1h, p0l, p1l, bs0, l, c1);
  __syncthreads();  // bs0 + tile reads retired before overwrite
#pragma unroll
  for (int tc = 0; tc < 4; ++tc) {
    float bv = c1b[lr + 16 * tc];
#pragma unroll
    for (int r = 0; r < 4; ++r) {
      float v = fmaxf(c1[tc][r] + bv, 0.f);
      int o = (16 * w + 4 * lg + r) * PITCH + lr + 16 * tc;
      ushort hh = f2bf(v);
      th[o] = hh;
      tl[o] = f2bf(v - bf2f(hh));
    }
  }
  stageB(c2p, bs0, t);
  __syncthreads();
  short8 q0h = *(const short8*)(th + abase);
  short8 q1h = *(const short8*)(th + abase + 32);
  short8 q0l = *(const short8*)(tl + abase);
  short8 q1l = *(const short8*)(tl + abase + 32);

  f32x4 c2[3];
#pragma unroll
  for (int tc = 0; tc < 3; ++tc) c2[tc] = (f32x4)0.f;
  mm_mfma_l<3>(q0h, q1h, q0l, q1l, bs0, l, c2);
#pragma unroll
  for (int tc = 0; tc < 3; ++tc) {
    int cc = lr + 16 * tc;
    if (cc < 40) {
      float bv = c2b[cc];
#pragma unroll
      for (int r = 0; r < 4; ++r) {
        int gn = blk * 64 + 16 * w + 4 * lg + r;
        if (gn < NN) outv[gn * 40 + cc] = c2[tc][r] + bv;
      }
    }
  }
}

// ---------------- launch ----------------

extern "C" void kernel_launch(void* const* d_in, const int* in_sizes, int n_in,
                              void* d_out, int out_size, void* d_ws, size_t ws_size,
                              hipStream_t stream) {
  (void)in_sizes; (void)n_in; (void)out_size; (void)ws_size;
  const float* x    = (const float*)d_in[0];
  const int*   ei   = (const int*)d_in[1];
  const float* Wh   = (const float*)d_in[2];
  const float* bh   = (const float*)d_in[3];
  const float* Wx   = (const float*)d_in[4];
  const float* bx   = (const float*)d_in[5];
  const float* gfw  = (const float*)d_in[6];
  const float* gfb  = (const float*)d_in[7];
  const float* guw  = (const float*)d_in[8];
  const float* gub  = (const float*)d_in[9];
  const float* ff1w = (const float*)d_in[10];
  const float* ff1b = (const float*)d_in[11];
  const float* ff2w = (const float*)d_in[12];
  const float* ff2b = (const float*)d_in[13];
  const float* c1w  = (const float*)d_in[14];
  const float* c1b  = (const float*)d_in[15];
  const float* c2w  = (const float*)d_in[16];
  const float* c2b  = (const float*)d_in[17];
  float* outv = (float*)d_out;

  char* ws = (char*)d_ws;
  size_t o = 0;
  auto take = [&](size_t b) { char* p = ws + o; o += (b + 255) & ~(size_t)255; return p; };
  int*    deg  = (int*)take((size_t)NN * 4);
  int*    rank = (int*)take((size_t)EE * 4);
  int*    rowp = (int*)take((size_t)(NN + 1) * 4);
  int*    bsum = (int*)take(512 * 4);
  int*    col  = (int*)take((size_t)EE * 4);
  float*  dinv = (float*)take((size_t)NN * 4);
  ushort* wpk  = (ushort*)take((size_t)22 * 8192 * 2);
  ushort* aggXP = (ushort*)take((size_t)NN * 128 * 2);
  ushort* aggHP = (ushort*)take((size_t)NN * 128 * 2);
  float*  hbuf = (float*)take((size_t)NN * 64 * 4);
  float*  xsc  = (float*)take((size_t)NN * 64 * 4);

  const int* srcv = ei;
  const int* dstv = ei + EE;

  const int NB_E = (EE + 255) / 256;
  const int NB_N = (NN + 255) / 256;
  const int NB_V4 = (NN * 16 + 255) / 256;

  k_packz<<<NB_N, 256, 0, stream>>>(Wh, Wx, ff1w, ff2w, c1w, c2w, wpk, deg);
  k_countrank<<<NB_E, 256, 0, stream>>>(dstv, deg, rank);
  k_scan1<<<NB_N, 256, 0, stream>>>(deg, rowp, bsum, dinv);
  k_scan2<<<1, 512, 0, stream>>>(bsum, rowp, NB_N);
  k_scan3<<<NB_N, 256, 0, stream>>>(rowp, bsum);
  k_fill<<<NB_E, 256, 0, stream>>>(srcv, dstv, rowp, rank, col);

  k_prescale<<<NB_V4, 256, 0, stream>>>(x, dinv, xsc);
  k_spmm<<<(NN + 15) / 16, 256, 0, stream>>>((const float4*)xsc, dinv, rowp, col, aggXP);

  const int NB_L = (NN + 63) / 64;
  // layer 0 (h=0); writes h1 (hbuf) and h1*dinv (xsc)
  k_layer<0, 1, 0><<<NB_L, 256, 0, stream>>>(
      aggXP, aggXP, hbuf, hbuf, xsc, dinv,
      wpk + 0 * 8192, wpk + 8 * 8192, bx, bh, gfw, gfb, guw, gub,
      wpk + 16 * 8192, ff1b, wpk + 18 * 8192, ff2b,
      wpk + 20 * 8192, c1b, wpk + 21 * 8192, c2b, outv);

  k_spmm<<<(NN + 15) / 16, 256, 0, stream>>>((const float4*)xsc, dinv, rowp, col, aggHP);

  // layer 1 + fused classifier -> outv
  k_layer<1, 0, 1><<<NB_L, 256, 0, stream>>>(
      aggXP, aggHP, hbuf, hbuf, xsc, dinv,
      wpk + 4 * 8192, wpk + 12 * 8192, bx + 256, bh + 256, gfw, gfb, guw, gub,
      wpk + 17 * 8192, ff1b + 64, wpk + 19 * 8192, ff2b + 64,
      wpk + 20 * 8192, c1b, wpk + 21 * 8192, c2b, outv);
}

// Round 19
// 335.595 us; speedup vs baseline: 1.0925x; 1.0925x over previous
//
#include <hip/hip_runtime.h>

#define NN 100000
#define EE 1200000
#define ALPHA_C 0.2f
#define EPS_C 1e-5f

typedef __attribute__((ext_vector_type(8))) short short8;
typedef __attribute__((ext_vector_type(4))) float f32x4;
#define MFMA __builtin_amdgcn_mfma_f32_16x16x32_bf16

#define PITCH 72  // LDS tile pitch (ushorts): 144B rows, 16B-aligned frags

// ---------------- bf16 helpers ----------------

__device__ __forceinline__ ushort f2bf(float f) {
  unsigned u = __float_as_uint(f);
  unsigned r = (u + 0x7FFFu + ((u >> 16) & 1u)) >> 16;
  return (ushort)r;
}
__device__ __forceinline__ float bf2f(ushort h) { return __uint_as_float((unsigned)h << 16); }

__device__ __forceinline__ float ftanh(float x) {  // validated (rounds 8/11/12/16 pass)
  float ax = fabsf(x);
  float e = __expf(2.f * ax);
  float t = 1.f - 2.f / (e + 1.f);
  return copysignf(t, x);
}

// ---------------- CSR build ----------------

__global__ __launch_bounds__(256) void k_countrank(const int* __restrict__ dstv,
                                                   int* __restrict__ deg, int* __restrict__ rank) {
  int e = blockIdx.x * 256 + threadIdx.x;
  if (e < EE) rank[e] = atomicAdd(&deg[dstv[e]], 1);
}

__global__ __launch_bounds__(256) void k_scan1(const int* __restrict__ deg, int* __restrict__ rowp,
                                               int* __restrict__ bsum, float* __restrict__ dinv) {
  __shared__ int s[256];
  int t = threadIdx.x;
  int i = blockIdx.x * 256 + t;
  int v = (i < NN) ? deg[i] : 0;
  if (i < NN) dinv[i] = rsqrtf((float)v + 1.0f);  // +1 self-loop
  s[t] = v;
  __syncthreads();
  for (int off = 1; off < 256; off <<= 1) {
    int add = (t >= off) ? s[t - off] : 0;
    __syncthreads();
    s[t] += add;
    __syncthreads();
  }
  if (i < NN) rowp[i] = s[t] - v;
  if (t == 255) bsum[blockIdx.x] = s[255];
}

__global__ __launch_bounds__(512) void k_scan2(int* __restrict__ bsum, int* __restrict__ rowp, int nb) {
  __shared__ int s[512];
  int t = threadIdx.x;
  int v = (t < nb) ? bsum[t] : 0;
  s[t] = v;
  __syncthreads();
  for (int off = 1; off < 512; off <<= 1) {
    int add = (t >= off) ? s[t - off] : 0;
    __syncthreads();
    s[t] += add;
    __syncthreads();
  }
  if (t < nb) bsum[t] = s[t] - v;
  if (t == 0) rowp[NN] = EE;
}

__global__ __launch_bounds__(256) void k_scan3(int* __restrict__ rowp, const int* __restrict__ bsum) {
  int i = blockIdx.x * 256 + threadIdx.x;
  if (i < NN) rowp[i] += bsum[blockIdx.x];
}

__global__ __launch_bounds__(256) void k_fill(const int* __restrict__ srcv, const int* __restrict__ dstv,
                                              const int* __restrict__ rowp, const int* __restrict__ rank,
                                              int* __restrict__ col) {
  int e = blockIdx.x * 256 + threadIdx.x;
  if (e < EE) col[rowp[dstv[e]] + rank[e]] = srcv[e];
}

// ---------------- SpMM ----------------

__global__ __launch_bounds__(256) void k_prescale(const float* __restrict__ feat,
                                                  const float* __restrict__ dinv,
                                                  float* __restrict__ xs) {
  int idx = blockIdx.x * 256 + threadIdx.x;
  if (idx < NN * 16) {
    float4 v = ((const float4*)feat)[idx];
    float d = dinv[idx >> 4];
    v.x *= d; v.y *= d; v.z *= d; v.w *= d;
    ((float4*)xs)[idx] = v;
  }
}

// out: packed bf16 hi||lo A-fragment layout, 128 ushorts/node ([64 hi][64 lo])
// 8-way unrolled gather (latency-bound: more outstanding loads per wave)
__global__ __launch_bounds__(256) void k_spmm(const float4* __restrict__ xs4, const float* __restrict__ dinv,
                                              const int* __restrict__ rowp, const int* __restrict__ col,
                                              ushort* __restrict__ outP) {
  int node = blockIdx.x * 16 + (threadIdx.x >> 4);
  int q = threadIdx.x & 15;
  if (node >= NN) return;
  int s = rowp[node], e = rowp[node + 1];
  float4 a0 = {0.f, 0.f, 0.f, 0.f}, a1 = a0, a2 = a0, a3 = a0;
  float4 a4 = a0, a5 = a0, a6 = a0, a7 = a0;
  int j = s;
  for (; j + 8 <= e; j += 8) {
    int c0 = col[j],     c1 = col[j + 1], c2 = col[j + 2], c3 = col[j + 3];
    int c4 = col[j + 4], c5 = col[j + 5], c6 = col[j + 6], c7 = col[j + 7];
    float4 v0 = xs4[c0 * 16 + q];
    float4 v1 = xs4[c1 * 16 + q];
    float4 v2 = xs4[c2 * 16 + q];
    float4 v3 = xs4[c3 * 16 + q];
    float4 v4 = xs4[c4 * 16 + q];
    float4 v5 = xs4[c5 * 16 + q];
    float4 v6 = xs4[c6 * 16 + q];
    float4 v7 = xs4[c7 * 16 + q];
    a0 += v0; a1 += v1; a2 += v2; a3 += v3;
    a4 += v4; a5 += v5; a6 += v6; a7 += v7;
  }
  for (; j + 4 <= e; j += 4) {
    int c0 = col[j], c1 = col[j + 1], c2 = col[j + 2], c3 = col[j + 3];
    float4 v0 = xs4[c0 * 16 + q];
    float4 v1 = xs4[c1 * 16 + q];
    float4 v2 = xs4[c2 * 16 + q];
    float4 v3 = xs4[c3 * 16 + q];
    a0 += v0; a1 += v1; a2 += v2; a3 += v3;
  }
  for (; j < e; ++j) a0 += xs4[col[j] * 16 + q];
  float4 sv = xs4[node * 16 + q];
  float d = dinv[node];
  a0 += a4; a1 += a5; a2 += a6; a3 += a7;
  float4 o;
  o.x = d * (a0.x + a1.x + a2.x + a3.x + sv.x);
  o.y = d * (a0.y + a1.y + a2.y + a3.y + sv.y);
  o.z = d * (a0.z + a1.z + a2.z + a3.z + sv.z);
  o.w = d * (a0.w + a1.w + a2.w + a3.w + sv.w);
  ushort h0 = f2bf(o.x), h1 = f2bf(o.y), h2 = f2bf(o.z), h3 = f2bf(o.w);
  ushort l0 = f2bf(o.x - bf2f(h0)), l1 = f2bf(o.y - bf2f(h1)),
         l2 = f2bf(o.z - bf2f(h2)), l3 = f2bf(o.w - bf2f(h3));
  ushort* p = outP + (size_t)node * 128 + 4 * q;
  *(ushort4*)(p) = make_ushort4(h0, h1, h2, h3);
  *(ushort4*)(p + 64) = make_ushort4(l0, l1, l2, l3);
}

// ---------------- weight pre-pack (B-fragment order, hi||lo bf16) + deg zero ----------

__global__ __launch_bounds__(256) void k_packz(const float* __restrict__ Wh, const float* __restrict__ Wx,
                                               const float* __restrict__ ff1w, const float* __restrict__ ff2w,
                                               const float* __restrict__ c1w, const float* __restrict__ c2w,
                                               ushort* __restrict__ wpk, int* __restrict__ deg) {
  int i = blockIdx.x * 256 + threadIdx.x;
  if (i < NN) deg[i] = 0;
  int id = blockIdx.x;
  if (id >= 22) return;
  const float* src;
  int ncol = 64, vcol = 64;
  if (id < 8) src = Wx + id * 4096;
  else if (id < 16) src = Wh + (id - 8) * 4096;
  else if (id < 18) src = ff1w + (id - 16) * 4096;
  else if (id < 20) src = ff2w + (id - 18) * 4096;
  else if (id == 20) src = c1w;
  else { src = c2w; ncol = 40; vcol = 40; }
  ushort* dst = wpk + (size_t)id * 8192;
  for (int p = threadIdx.x; p < 512; p += 256) {
    int f = p >> 6, l = p & 63;
    int kh = f & 1, tc = f >> 1;
    int r0 = 32 * kh + 8 * (l >> 4), c = 16 * tc + (l & 15);
#pragma unroll
    for (int j = 0; j < 8; ++j) {
      float v = (c < vcol) ? src[(r0 + j) * ncol + c] : 0.f;
      ushort h = f2bf(v);
      dst[f * 512 + l * 8 + j] = h;
      dst[4096 + f * 512 + l * 8 + j] = f2bf(v - bf2f(h));
    }
  }
}

// ---------------- dense helpers ----------------

__device__ __forceinline__ float red16(float v) {
  v += __shfl_xor(v, 1);
  v += __shfl_xor(v, 2);
  v += __shfl_xor(v, 4);
  v += __shfl_xor(v, 8);
  return v;
}

__device__ __forceinline__ void stageB(const ushort* __restrict__ wp, ushort* __restrict__ bsta, int t) {
#pragma unroll
  for (int u = 0; u < 4; ++u) {
    int o = (u * 256 + t) * 8;
    *(short8*)(bsta + o) = *(const short8*)(wp + o);
  }
}

template <int NT>
__device__ __forceinline__ void mm_mfma_l(short8 a0h, short8 a1h, short8 a0l, short8 a1l,
                                          const ushort* __restrict__ bsta, int l, f32x4* C) {
#pragma unroll
  for (int tc = 0; tc < NT; ++tc) {
#pragma unroll
    for (int kh = 0; kh < 2; ++kh) {
      const short8 bh = *(const short8*)(bsta + (tc * 2 + kh) * 512 + l * 8);
      const short8 bl = *(const short8*)(bsta + 4096 + (tc * 2 + kh) * 512 + l * 8);
      const short8 ah = kh ? a1h : a0h;
      const short8 alo = kh ? a1l : a0l;
      C[tc] = MFMA(ah, bh, C[tc], 0, 0, 0);
      C[tc] = MFMA(ah, bl, C[tc], 0, 0, 0);
      C[tc] = MFMA(alo, bh, C[tc], 0, 0, 0);
    }
  }
}

__device__ __forceinline__ void ln_frag(float v[4][4]) {
#pragma unroll
  for (int r = 0; r < 4; ++r) {
    float s = v[0][r] + v[1][r] + v[2][r] + v[3][r];
    s = red16(s);
    float mu = s * 0.015625f;
    float q = 0.f;
#pragma unroll
    for (int tc = 0; tc < 4; ++tc) { float d = v[tc][r] - mu; q = fmaf(d, d, q); }
    q = red16(q);
    float inv = rsqrtf(q * 0.015625f + EPS_C);
#pragma unroll
    for (int tc = 0; tc < 4; ++tc) v[tc][r] = (v[tc][r] - mu) * inv;
  }
}

// ---------------- fused per-layer kernel (r16 proven structure, runtime head loop) ------
// 64 nodes/block, 4 waves; dual-buffer head staging (bs0=Wx_k, bs1=Wh_k), 2 barriers/head.
// C/D frag: row = 16w + 4*(l>>4) + r, col = (l&15) + 16*tc.

template <int HAS_H, int WSC, int DO_CLF>
__global__ __launch_bounds__(256) void k_layer(
    const ushort* __restrict__ aggXP, const ushort* __restrict__ aggHP,
    const float* __restrict__ h_in, float* __restrict__ h_out,
    float* __restrict__ hs_out, const float* __restrict__ dinv,
    const ushort* __restrict__ wxp, const ushort* __restrict__ whp,
    const float* __restrict__ bxl, const float* __restrict__ bhl,
    const float* __restrict__ gfw, const float* __restrict__ gfb,
    const float* __restrict__ guw, const float* __restrict__ gub,
    const ushort* __restrict__ ff1p, const float* __restrict__ ff1b,
    const ushort* __restrict__ ff2p, const float* __restrict__ ff2b,
    const ushort* __restrict__ c1p, const float* __restrict__ c1b,
    const ushort* __restrict__ c2p, const float* __restrict__ c2b,
    float* __restrict__ outv) {
  __shared__ __align__(16) ushort th[64 * PITCH], tl[64 * PITCH];
  __shared__ __align__(16) ushort bs0[8192], bs1[8192];
  const int t = threadIdx.x, blk = blockIdx.x;
  const int w = t >> 6, l = t & 63, lg = l >> 4, lr = l & 15;
  const int abase = (16 * w + lr) * PITCH + 8 * lg;
  const int arow = blk * 64 + 16 * w + lr;
  const int arowc = arow < NN ? arow : NN - 1;

  const ushort* axp = aggXP + (size_t)arowc * 128 + 8 * lg;
  short8 xa0h = *(const short8*)(axp);
  short8 xa1h = *(const short8*)(axp + 32);
  short8 xa0l = *(const short8*)(axp + 64);
  short8 xa1l = *(const short8*)(axp + 96);
  short8 ha0h = (short8)0, ha1h = (short8)0, ha0l = (short8)0, ha1l = (short8)0;
  if (HAS_H) {
    const ushort* ahp = aggHP + (size_t)arowc * 128 + 8 * lg;
    ha0h = *(const short8*)(ahp);
    ha1h = *(const short8*)(ahp + 32);
    ha0l = *(const short8*)(ahp + 64);
    ha1l = *(const short8*)(ahp + 96);
  }

  float gfhw[4], gfxw[4], guhw[4], guxw[4];
#pragma unroll
  for (int tc = 0; tc < 4; ++tc) {
    gfhw[tc] = gfw[lr + 16 * tc]; gfxw[tc] = gfw[64 + lr + 16 * tc];
    guhw[tc] = guw[lr + 16 * tc]; guxw[tc] = guw[64 + lr + 16 * tc];
  }
  const float gfb0 = gfb[0], gub0 = gub[0];

  float acc[4][4];
#pragma unroll
  for (int tc = 0; tc < 4; ++tc)
#pragma unroll
    for (int r = 0; r < 4; ++r) acc[tc][r] = 0.f;

  // ---- head loop: dual-buffer stage, 2 barriers per head (runtime loop — r16 proven) ----
  for (int k = 0; k < 4; ++k) {
    f32x4 cx[4], ch[4];
#pragma unroll
    for (int tc = 0; tc < 4; ++tc) { cx[tc] = (f32x4)0.f; ch[tc] = (f32x4)0.f; }
    __syncthreads();  // prior readers of bs0/bs1 done
    stageB(wxp + k * 8192, bs0, t);
    if (HAS_H) stageB(whp + k * 8192, bs1, t);
    __syncthreads();  // staged
    mm_mfma_l<4>(xa0h, xa1h, xa0l, xa1l, bs0, l, cx);
    if (HAS_H) mm_mfma_l<4>(ha0h, ha1h, ha0l, ha1l, bs1, l, ch);

    float Cx[4][4], Ch[4][4];
#pragma unroll
    for (int tc = 0; tc < 4; ++tc) {
      float bxv = bxl[k * 64 + lr + 16 * tc];
      float bhv = bhl[k * 64 + lr + 16 * tc];
#pragma unroll
      for (int r = 0; r < 4; ++r) {
        Cx[tc][r] = cx[tc][r] + bxv;
        Ch[tc][r] = (HAS_H ? ch[tc][r] : 0.f) + bhv;
      }
    }
#pragma unroll
    for (int r = 0; r < 4; ++r) {
      float pf = 0.f, pu = 0.f;
#pragma unroll
      for (int tc = 0; tc < 4; ++tc) {
        pf = fmaf(Ch[tc][r], gfhw[tc], pf); pf = fmaf(Cx[tc][r], gfxw[tc], pf);
        pu = fmaf(Ch[tc][r], guhw[tc], pu); pu = fmaf(Cx[tc][r], guxw[tc], pu);
      }
      pf = red16(pf); pu = red16(pu);
      float fv = ALPHA_C * ftanh(pf + gfb0);
      float uv = ALPHA_C * ftanh(pu + gub0);
#pragma unroll
      for (int tc = 0; tc < 4; ++tc)
        acc[tc][r] += (1.f + fv) * Ch[tc][r] + (1.f + uv) * Cx[tc][r];
    }
  }

  // hmid = acc/4 + h_in ; LN
  float hmid[4][4];
#pragma unroll
  for (int tc = 0; tc < 4; ++tc)
#pragma unroll
    for (int r = 0; r < 4; ++r) {
      float hv = 0.f;
      if (HAS_H) {
        int gn = blk * 64 + 16 * w + 4 * lg + r;
        if (gn > NN - 1) gn = NN - 1;
        hv = h_in[gn * 64 + lr + 16 * tc];
      }
      hmid[tc][r] = fmaf(acc[tc][r], 0.25f, hv);
    }
  ln_frag(hmid);

  __syncthreads();  // all waves past last head phase (bs0/bs1 reads retired)
#pragma unroll
  for (int tc = 0; tc < 4; ++tc)
#pragma unroll
    for (int r = 0; r < 4; ++r) {
      int o = (16 * w + 4 * lg + r) * PITCH + lr + 16 * tc;
      ushort h = f2bf(hmid[tc][r]);
      th[o] = h;
      tl[o] = f2bf(hmid[tc][r] - bf2f(h));
    }
  __syncthreads();
  short8 m0h = *(const short8*)(th + abase);
  short8 m1h = *(const short8*)(th + abase + 32);
  short8 m0l = *(const short8*)(tl + abase);
  short8 m1l = *(const short8*)(tl + abase + 32);

  f32x4 f1[4];
#pragma unroll
  for (int tc = 0; tc < 4; ++tc) f1[tc] = (f32x4)0.f;
  __syncthreads();  // m-frag reads done (held in regs) before bs0 restage
  stageB(ff1p, bs0, t);
  __syncthreads();
  mm_mfma_l<4>(m0h, m1h, m0l, m1l, bs0, l, f1);
#pragma unroll
  for (int tc = 0; tc < 4; ++tc) {
    float bv = ff1b[lr + 16 * tc];
#pragma unroll
    for (int r = 0; r < 4; ++r) {
      float v = fmaxf(f1[tc][r] + bv, 0.f);
      int o = (16 * w + 4 * lg + r) * PITCH + lr + 16 * tc;
      ushort h = f2bf(v);
      th[o] = h;
      tl[o] = f2bf(v - bf2f(h));
    }
  }
  __syncthreads();
  short8 g0h = *(const short8*)(th + abase);
  short8 g1h = *(const short8*)(th + abase + 32);
  short8 g0l = *(const short8*)(tl + abase);
  short8 g1l = *(const short8*)(tl + abase + 32);

  f32x4 f2[4];
#pragma unroll
  for (int tc = 0; tc < 4; ++tc) f2[tc] = (f32x4)0.f;
  __syncthreads();
  stageB(ff2p, bs0, t);
  __syncthreads();
  mm_mfma_l<4>(g0h, g1h, g0l, g1l, bs0, l, f2);
  float F2[4][4];
#pragma unroll
  for (int tc = 0; tc < 4; ++tc) {
    float bv = ff2b[lr + 16 * tc];
#pragma unroll
    for (int r = 0; r < 4; ++r) F2[tc][r] = f2[tc][r] + bv + hmid[tc][r];
  }
  ln_frag(F2);

  if (!DO_CLF) {
#pragma unroll
    for (int r = 0; r < 4; ++r) {
      int gn = blk * 64 + 16 * w + 4 * lg + r;
      if (gn < NN) {
        float dv = WSC ? dinv[gn] : 0.f;
#pragma unroll
        for (int tc = 0; tc < 4; ++tc) {
          h_out[gn * 64 + lr + 16 * tc] = F2[tc][r];
          if (WSC) hs_out[gn * 64 + lr + 16 * tc] = F2[tc][r] * dv;
        }
      }
    }
    return;
  }

  // ===== classifier tail =====
  __syncthreads();  // all waves past FF2 mm (bs0 + tile reads retired)
#pragma unroll
  for (int tc = 0; tc < 4; ++tc)
#pragma unroll
    for (int r = 0; r < 4; ++r) {
      int o = (16 * w + 4 * lg + r) * PITCH + lr + 16 * tc;
      ushort h = f2bf(F2[tc][r]);
      th[o] = h;
      tl[o] = f2bf(F2[tc][r] - bf2f(h));
    }
  stageB(c1p, bs0, t);
  __syncthreads();
  short8 p0h = *(const short8*)(th + abase);
  short8 p1h = *(const short8*)(th + abase + 32);
  short8 p0l = *(const short8*)(tl + abase);
  short8 p1l = *(const short8*)(tl + abase + 32);

  f32x4 c1[4];
#pragma unroll
  for (int tc = 0; tc < 4; ++tc) c1[tc] = (f32x4)0.f;
  mm_mfma_l<4>(p0h, p1h, p0l, p1l, bs0, l, c1);
  __syncthreads();  // bs0 + tile reads retired before overwrite
#pragma unroll
  for (int tc = 0; tc < 4; ++tc) {
    float bv = c1b[lr + 16 * tc];
#pragma unroll
    for (int r = 0; r < 4; ++r) {
      float v = fmaxf(c1[tc][r] + bv, 0.f);
      int o = (16 * w + 4 * lg + r) * PITCH + lr + 16 * tc;
      ushort hh = f2bf(v);
      th[o] = hh;
      tl[o] = f2bf(v - bf2f(hh));
    }
  }
  stageB(c2p, bs0, t);
  __syncthreads();
  short8 q0h = *(const short8*)(th + abase);
  short8 q1h = *(const short8*)(th + abase + 32);
  short8 q0l = *(const short8*)(tl + abase);
  short8 q1l = *(const short8*)(tl + abase + 32);

  f32x4 c2[3];
#pragma unroll
  for (int tc = 0; tc < 3; ++tc) c2[tc] = (f32x4)0.f;
  mm_mfma_l<3>(q0h, q1h, q0l, q1l, bs0, l, c2);
#pragma unroll
  for (int tc = 0; tc < 3; ++tc) {
    int cc = lr + 16 * tc;
    if (cc < 40) {
      float bv = c2b[cc];
#pragma unroll
      for (int r = 0; r < 4; ++r) {
        int gn = blk * 64 + 16 * w + 4 * lg + r;
        if (gn < NN) outv[gn * 40 + cc] = c2[tc][r] + bv;
      }
    }
  }
}

// ---------------- launch ----------------

extern "C" void kernel_launch(void* const* d_in, const int* in_sizes, int n_in,
                              void* d_out, int out_size, void* d_ws, size_t ws_size,
                              hipStream_t stream) {
  (void)in_sizes; (void)n_in; (void)out_size; (void)ws_size;
  const float* x    = (const float*)d_in[0];
  const int*   ei   = (const int*)d_in[1];
  const float* Wh   = (const float*)d_in[2];
  const float* bh   = (const float*)d_in[3];
  const float* Wx   = (const float*)d_in[4];
  const float* bx   = (const float*)d_in[5];
  const float* gfw  = (const float*)d_in[6];
  const float* gfb  = (const float*)d_in[7];
  const float* guw  = (const float*)d_in[8];
  const float* gub  = (const float*)d_in[9];
  const float* ff1w = (const float*)d_in[10];
  const float* ff1b = (const float*)d_in[11];
  const float* ff2w = (const float*)d_in[12];
  const float* ff2b = (const float*)d_in[13];
  const float* c1w  = (const float*)d_in[14];
  const float* c1b  = (const float*)d_in[15];
  const float* c2w  = (const float*)d_in[16];
  const float* c2b  = (const float*)d_in[17];
  float* outv = (float*)d_out;

  char* ws = (char*)d_ws;
  size_t o = 0;
  auto take = [&](size_t b) { char* p = ws + o; o += (b + 255) & ~(size_t)255; return p; };
  int*    deg  = (int*)take((size_t)NN * 4);
  int*    rank = (int*)take((size_t)EE * 4);
  int*    rowp = (int*)take((size_t)(NN + 1) * 4);
  int*    bsum = (int*)take(512 * 4);
  int*    col  = (int*)take((size_t)EE * 4);
  float*  dinv = (float*)take((size_t)NN * 4);
  ushort* wpk  = (ushort*)take((size_t)22 * 8192 * 2);
  ushort* aggXP = (ushort*)take((size_t)NN * 128 * 2);
  ushort* aggHP = (ushort*)take((size_t)NN * 128 * 2);
  float*  hbuf = (float*)take((size_t)NN * 64 * 4);
  float*  xsc  = (float*)take((size_t)NN * 64 * 4);

  const int* srcv = ei;
  const int* dstv = ei + EE;

  const int NB_E = (EE + 255) / 256;
  const int NB_N = (NN + 255) / 256;
  const int NB_V4 = (NN * 16 + 255) / 256;

  k_packz<<<NB_N, 256, 0, stream>>>(Wh, Wx, ff1w, ff2w, c1w, c2w, wpk, deg);
  k_countrank<<<NB_E, 256, 0, stream>>>(dstv, deg, rank);
  k_scan1<<<NB_N, 256, 0, stream>>>(deg, rowp, bsum, dinv);
  k_scan2<<<1, 512, 0, stream>>>(bsum, rowp, NB_N);
  k_scan3<<<NB_N, 256, 0, stream>>>(rowp, bsum);
  k_fill<<<NB_E, 256, 0, stream>>>(srcv, dstv, rowp, rank, col);

  k_prescale<<<NB_V4, 256, 0, stream>>>(x, dinv, xsc);
  k_spmm<<<(NN + 15) / 16, 256, 0, stream>>>((const float4*)xsc, dinv, rowp, col, aggXP);

  const int NB_L = (NN + 63) / 64;
  // layer 0 (h=0); writes h1 (hbuf) and h1*dinv (xsc)
  k_layer<0, 1, 0><<<NB_L, 256, 0, stream>>>(
      aggXP, aggXP, hbuf, hbuf, xsc, dinv,
      wpk + 0 * 8192, wpk + 8 * 8192, bx, bh, gfw, gfb, guw, gub,
      wpk + 16 * 8192, ff1b, wpk + 18 * 8192, ff2b,
      wpk + 20 * 8192, c1b, wpk + 21 * 8192, c2b, outv);

  k_spmm<<<(NN + 15) / 16, 256, 0, stream>>>((const float4*)xsc, dinv, rowp, col, aggHP);

  // layer 1 + fused classifier -> outv
  k_layer<1, 0, 1><<<NB_L, 256, 0, stream>>>(
      aggXP, aggHP, hbuf, hbuf, xsc, dinv,
      wpk + 4 * 8192, wpk + 12 * 8192, bx + 256, bh + 256, gfw, gfb, guw, gub,
      wpk + 17 * 8192, ff1b + 64, wpk + 19 * 8192, ff2b + 64,
      wpk + 20 * 8192, c1b, wpk + 21 * 8192, c2b, outv);
}

// Round 20
// 334.040 us; speedup vs baseline: 1.0976x; 1.0047x over previous
//
#include <hip/hip_runtime.h>

#define NN 100000
#define EE 1200000
#define ALPHA_C 0.2f
#define EPS_C 1e-5f

typedef __attribute__((ext_vector_type(8))) short short8;
typedef __attribute__((ext_vector_type(4))) float f32x4;
#define MFMA __builtin_amdgcn_mfma_f32_16x16x32_bf16

#define PITCH 72  // LDS tile pitch (ushorts): 144B rows, 16B-aligned frags

// ---------------- bf16 helpers ----------------

__device__ __forceinline__ ushort f2bf(float f) {
  unsigned u = __float_as_uint(f);
  unsigned r = (u + 0x7FFFu + ((u >> 16) & 1u)) >> 16;
  return (ushort)r;
}
__device__ __forceinline__ float bf2f(ushort h) { return __uint_as_float((unsigned)h << 16); }

__device__ __forceinline__ float ftanh(float x) {  // validated (rounds 8/11/12/16/19 pass)
  float ax = fabsf(x);
  float e = __expf(2.f * ax);
  float t = 1.f - 2.f / (e + 1.f);
  return copysignf(t, x);
}

// ---------------- CSR build ----------------

__global__ __launch_bounds__(256) void k_countrank(const int* __restrict__ dstv,
                                                   int* __restrict__ deg, int* __restrict__ rank) {
  int e = blockIdx.x * 256 + threadIdx.x;
  if (e < EE) rank[e] = atomicAdd(&deg[dstv[e]], 1);
}

__global__ __launch_bounds__(256) void k_scan1(const int* __restrict__ deg, int* __restrict__ rowp,
                                               int* __restrict__ bsum, float* __restrict__ dinv) {
  __shared__ int s[256];
  int t = threadIdx.x;
  int i = blockIdx.x * 256 + t;
  int v = (i < NN) ? deg[i] : 0;
  if (i < NN) dinv[i] = rsqrtf((float)v + 1.0f);  // +1 self-loop
  s[t] = v;
  __syncthreads();
  for (int off = 1; off < 256; off <<= 1) {
    int add = (t >= off) ? s[t - off] : 0;
    __syncthreads();
    s[t] += add;
    __syncthreads();
  }
  if (i < NN) rowp[i] = s[t] - v;
  if (t == 255) bsum[blockIdx.x] = s[255];
}

__global__ __launch_bounds__(512) void k_scan2(int* __restrict__ bsum, int* __restrict__ rowp, int nb) {
  __shared__ int s[512];
  int t = threadIdx.x;
  int v = (t < nb) ? bsum[t] : 0;
  s[t] = v;
  __syncthreads();
  for (int off = 1; off < 512; off <<= 1) {
    int add = (t >= off) ? s[t - off] : 0;
    __syncthreads();
    s[t] += add;
    __syncthreads();
  }
  if (t < nb) bsum[t] = s[t] - v;
  if (t == 0) rowp[NN] = EE;
}

__global__ __launch_bounds__(256) void k_scan3(int* __restrict__ rowp, const int* __restrict__ bsum) {
  int i = blockIdx.x * 256 + threadIdx.x;
  if (i < NN) rowp[i] += bsum[blockIdx.x];
}

// fused: blocks [0, NB_E) fill col via precomputed rank; blocks [NB_E, ..) prescale x by dinv
#define NB_E_C ((EE + 255) / 256)
__global__ __launch_bounds__(256) void k_fillpre(const int* __restrict__ srcv, const int* __restrict__ dstv,
                                                 const int* __restrict__ rowp, const int* __restrict__ rank,
                                                 int* __restrict__ col,
                                                 const float* __restrict__ feat, const float* __restrict__ dinv,
                                                 float* __restrict__ xs) {
  int b = blockIdx.x;
  if (b < NB_E_C) {
    int e = b * 256 + threadIdx.x;
    if (e < EE) col[rowp[dstv[e]] + rank[e]] = srcv[e];
  } else {
    int idx = (b - NB_E_C) * 256 + threadIdx.x;
    if (idx < NN * 16) {
      float4 v = ((const float4*)feat)[idx];
      float d = dinv[idx >> 4];
      v.x *= d; v.y *= d; v.z *= d; v.w *= d;
      ((float4*)xs)[idx] = v;
    }
  }
}

// standalone prescale (used for h between layers)
__global__ __launch_bounds__(256) void k_prescale(const float* __restrict__ feat,
                                                  const float* __restrict__ dinv,
                                                  float* __restrict__ xs) {
  int idx = blockIdx.x * 256 + threadIdx.x;
  if (idx < NN * 16) {
    float4 v = ((const float4*)feat)[idx];
    float d = dinv[idx >> 4];
    v.x *= d; v.y *= d; v.z *= d; v.w *= d;
    ((float4*)xs)[idx] = v;
  }
}

// ---------------- SpMM ----------------
// out: packed bf16 hi||lo A-fragment layout, 128 ushorts/node ([64 hi][64 lo])
// 8-way unrolled gather (latency-bound: more outstanding loads per wave)
__global__ __launch_bounds__(256) void k_spmm(const float4* __restrict__ xs4, const float* __restrict__ dinv,
                                              const int* __restrict__ rowp, const int* __restrict__ col,
                                              ushort* __restrict__ outP) {
  int node = blockIdx.x * 16 + (threadIdx.x >> 4);
  int q = threadIdx.x & 15;
  if (node >= NN) return;
  int s = rowp[node], e = rowp[node + 1];
  float4 a0 = {0.f, 0.f, 0.f, 0.f}, a1 = a0, a2 = a0, a3 = a0;
  float4 a4 = a0, a5 = a0, a6 = a0, a7 = a0;
  int j = s;
  for (; j + 8 <= e; j += 8) {
    int c0 = col[j],     c1 = col[j + 1], c2 = col[j + 2], c3 = col[j + 3];
    int c4 = col[j + 4], c5 = col[j + 5], c6 = col[j + 6], c7 = col[j + 7];
    float4 v0 = xs4[c0 * 16 + q];
    float4 v1 = xs4[c1 * 16 + q];
    float4 v2 = xs4[c2 * 16 + q];
    float4 v3 = xs4[c3 * 16 + q];
    float4 v4 = xs4[c4 * 16 + q];
    float4 v5 = xs4[c5 * 16 + q];
    float4 v6 = xs4[c6 * 16 + q];
    float4 v7 = xs4[c7 * 16 + q];
    a0 += v0; a1 += v1; a2 += v2; a3 += v3;
    a4 += v4; a5 += v5; a6 += v6; a7 += v7;
  }
  for (; j + 4 <= e; j += 4) {
    int c0 = col[j], c1 = col[j + 1], c2 = col[j + 2], c3 = col[j + 3];
    float4 v0 = xs4[c0 * 16 + q];
    float4 v1 = xs4[c1 * 16 + q];
    float4 v2 = xs4[c2 * 16 + q];
    float4 v3 = xs4[c3 * 16 + q];
    a0 += v0; a1 += v1; a2 += v2; a3 += v3;
  }
  for (; j < e; ++j) a0 += xs4[col[j] * 16 + q];
  float4 sv = xs4[node * 16 + q];
  float d = dinv[node];
  a0 += a4; a1 += a5; a2 += a6; a3 += a7;
  float4 o;
  o.x = d * (a0.x + a1.x + a2.x + a3.x + sv.x);
  o.y = d * (a0.y + a1.y + a2.y + a3.y + sv.y);
  o.z = d * (a0.z + a1.z + a2.z + a3.z + sv.z);
  o.w = d * (a0.w + a1.w + a2.w + a3.w + sv.w);
  ushort h0 = f2bf(o.x), h1 = f2bf(o.y), h2 = f2bf(o.z), h3 = f2bf(o.w);
  ushort l0 = f2bf(o.x - bf2f(h0)), l1 = f2bf(o.y - bf2f(h1)),
         l2 = f2bf(o.z - bf2f(h2)), l3 = f2bf(o.w - bf2f(h3));
  ushort* p = outP + (size_t)node * 128 + 4 * q;
  *(ushort4*)(p) = make_ushort4(h0, h1, h2, h3);
  *(ushort4*)(p + 64) = make_ushort4(l0, l1, l2, l3);
}

// ---------------- weight pre-pack (B-fragment order, hi||lo bf16) + deg zero ----------

__global__ __launch_bounds__(256) void k_packz(const float* __restrict__ Wh, const float* __restrict__ Wx,
                                               const float* __restrict__ ff1w, const float* __restrict__ ff2w,
                                               const float* __restrict__ c1w, const float* __restrict__ c2w,
                                               ushort* __restrict__ wpk, int* __restrict__ deg) {
  int i = blockIdx.x * 256 + threadIdx.x;
  if (i < NN) deg[i] = 0;
  int id = blockIdx.x;
  if (id >= 22) return;
  const float* src;
  int ncol = 64, vcol = 64;
  if (id < 8) src = Wx + id * 4096;
  else if (id < 16) src = Wh + (id - 8) * 4096;
  else if (id < 18) src = ff1w + (id - 16) * 4096;
  else if (id < 20) src = ff2w + (id - 18) * 4096;
  else if (id == 20) src = c1w;
  else { src = c2w; ncol = 40; vcol = 40; }
  ushort* dst = wpk + (size_t)id * 8192;
  for (int p = threadIdx.x; p < 512; p += 256) {
    int f = p >> 6, l = p & 63;
    int kh = f & 1, tc = f >> 1;
    int r0 = 32 * kh + 8 * (l >> 4), c = 16 * tc + (l & 15);
#pragma unroll
    for (int j = 0; j < 8; ++j) {
      float v = (c < vcol) ? src[(r0 + j) * ncol + c] : 0.f;
      ushort h = f2bf(v);
      dst[f * 512 + l * 8 + j] = h;
      dst[4096 + f * 512 + l * 8 + j] = f2bf(v - bf2f(h));
    }
  }
}

// ---------------- dense helpers ----------------

__device__ __forceinline__ float red16(float v) {
  v += __shfl_xor(v, 1);
  v += __shfl_xor(v, 2);
  v += __shfl_xor(v, 4);
  v += __shfl_xor(v, 8);
  return v;
}

__device__ __forceinline__ void stageB(const ushort* __restrict__ wp, ushort* __restrict__ bsta, int t) {
#pragma unroll
  for (int u = 0; u < 4; ++u) {
    int o = (u * 256 + t) * 8;
    *(short8*)(bsta + o) = *(const short8*)(wp + o);
  }
}

template <int NT>
__device__ __forceinline__ void mm_mfma_l(short8 a0h, short8 a1h, short8 a0l, short8 a1l,
                                          const ushort* __restrict__ bsta, int l, f32x4* C) {
#pragma unroll
  for (int tc = 0; tc < NT; ++tc) {
#pragma unroll
    for (int kh = 0; kh < 2; ++kh) {
      const short8 bh = *(const short8*)(bsta + (tc * 2 + kh) * 512 + l * 8);
      const short8 bl = *(const short8*)(bsta + 4096 + (tc * 2 + kh) * 512 + l * 8);
      const short8 ah = kh ? a1h : a0h;
      const short8 alo = kh ? a1l : a0l;
      C[tc] = MFMA(ah, bh, C[tc], 0, 0, 0);
      C[tc] = MFMA(ah, bl, C[tc], 0, 0, 0);
      C[tc] = MFMA(alo, bh, C[tc], 0, 0, 0);
    }
  }
}

__device__ __forceinline__ void ln_frag(float v[4][4]) {
#pragma unroll
  for (int r = 0; r < 4; ++r) {
    float s = v[0][r] + v[1][r] + v[2][r] + v[3][r];
    s = red16(s);
    float mu = s * 0.015625f;
    float q = 0.f;
#pragma unroll
    for (int tc = 0; tc < 4; ++tc) { float d = v[tc][r] - mu; q = fmaf(d, d, q); }
    q = red16(q);
    float inv = rsqrtf(q * 0.015625f + EPS_C);
#pragma unroll
    for (int tc = 0; tc < 4; ++tc) v[tc][r] = (v[tc][r] - mu) * inv;
  }
}

// ---------------- fused per-layer kernel (r16 proven structure, runtime head loop) ------
// 64 nodes/block, 4 waves; dual-buffer head staging (bs0=Wx_k, bs1=Wh_k), 2 barriers/head.
// C/D frag: row = 16w + 4*(l>>4) + r, col = (l&15) + 16*tc.

template <int HAS_H, int WSC, int DO_CLF>
__global__ __launch_bounds__(256) void k_layer(
    const ushort* __restrict__ aggXP, const ushort* __restrict__ aggHP,
    const float* __restrict__ h_in, float* __restrict__ h_out,
    float* __restrict__ hs_out, const float* __restrict__ dinv,
    const ushort* __restrict__ wxp, const ushort* __restrict__ whp,
    const float* __restrict__ bxl, const float* __restrict__ bhl,
    const float* __restrict__ gfw, const float* __restrict__ gfb,
    const float* __restrict__ guw, const float* __restrict__ gub,
    const ushort* __restrict__ ff1p, const float* __restrict__ ff1b,
    const ushort* __restrict__ ff2p, const float* __restrict__ ff2b,
    const ushort* __restrict__ c1p, const float* __restrict__ c1b,
    const ushort* __restrict__ c2p, const float* __restrict__ c2b,
    float* __restrict__ outv) {
  __shared__ __align__(16) ushort th[64 * PITCH], tl[64 * PITCH];
  __shared__ __align__(16) ushort bs0[8192], bs1[8192];
  const int t = threadIdx.x, blk = blockIdx.x;
  const int w = t >> 6, l = t & 63, lg = l >> 4, lr = l & 15;
  const int abase = (16 * w + lr) * PITCH + 8 * lg;
  const int arow = blk * 64 + 16 * w + lr;
  const int arowc = arow < NN ? arow : NN - 1;

  const ushort* axp = aggXP + (size_t)arowc * 128 + 8 * lg;
  short8 xa0h = *(const short8*)(axp);
  short8 xa1h = *(const short8*)(axp + 32);
  short8 xa0l = *(const short8*)(axp + 64);
  short8 xa1l = *(const short8*)(axp + 96);
  short8 ha0h = (short8)0, ha1h = (short8)0, ha0l = (short8)0, ha1l = (short8)0;
  if (HAS_H) {
    const ushort* ahp = aggHP + (size_t)arowc * 128 + 8 * lg;
    ha0h = *(const short8*)(ahp);
    ha1h = *(const short8*)(ahp + 32);
    ha0l = *(const short8*)(ahp + 64);
    ha1l = *(const short8*)(ahp + 96);
  }

  float gfhw[4], gfxw[4], guhw[4], guxw[4];
#pragma unroll
  for (int tc = 0; tc < 4; ++tc) {
    gfhw[tc] = gfw[lr + 16 * tc]; gfxw[tc] = gfw[64 + lr + 16 * tc];
    guhw[tc] = guw[lr + 16 * tc]; guxw[tc] = guw[64 + lr + 16 * tc];
  }
  const float gfb0 = gfb[0], gub0 = gub[0];

  float acc[4][4];
#pragma unroll
  for (int tc = 0; tc < 4; ++tc)
#pragma unroll
    for (int r = 0; r < 4; ++r) acc[tc][r] = 0.f;

  // ---- head loop: dual-buffer stage, 2 barriers per head (runtime loop — proven) ----
  for (int k = 0; k < 4; ++k) {
    f32x4 cx[4], ch[4];
#pragma unroll
    for (int tc = 0; tc < 4; ++tc) { cx[tc] = (f32x4)0.f; ch[tc] = (f32x4)0.f; }
    __syncthreads();  // prior readers of bs0/bs1 done
    stageB(wxp + k * 8192, bs0, t);
    if (HAS_H) stageB(whp + k * 8192, bs1, t);
    __syncthreads();  // staged
    mm_mfma_l<4>(xa0h, xa1h, xa0l, xa1l, bs0, l, cx);
    if (HAS_H) mm_mfma_l<4>(ha0h, ha1h, ha0l, ha1l, bs1, l, ch);

    float Cx[4][4], Ch[4][4];
#pragma unroll
    for (int tc = 0; tc < 4; ++tc) {
      float bxv = bxl[k * 64 + lr + 16 * tc];
      float bhv = bhl[k * 64 + lr + 16 * tc];
#pragma unroll
      for (int r = 0; r < 4; ++r) {
        Cx[tc][r] = cx[tc][r] + bxv;
        Ch[tc][r] = (HAS_H ? ch[tc][r] : 0.f) + bhv;
      }
    }
#pragma unroll
    for (int r = 0; r < 4; ++r) {
      float pf = 0.f, pu = 0.f;
#pragma unroll
      for (int tc = 0; tc < 4; ++tc) {
        pf = fmaf(Ch[tc][r], gfhw[tc], pf); pf = fmaf(Cx[tc][r], gfxw[tc], pf);
        pu = fmaf(Ch[tc][r], guhw[tc], pu); pu = fmaf(Cx[tc][r], guxw[tc], pu);
      }
      pf = red16(pf); pu = red16(pu);
      float fv = ALPHA_C * ftanh(pf + gfb0);
      float uv = ALPHA_C * ftanh(pu + gub0);
#pragma unroll
      for (int tc = 0; tc < 4; ++tc)
        acc[tc][r] += (1.f + fv) * Ch[tc][r] + (1.f + uv) * Cx[tc][r];
    }
  }

  // hmid = acc/4 + h_in ; LN
  float hmid[4][4];
#pragma unroll
  for (int tc = 0; tc < 4; ++tc)
#pragma unroll
    for (int r = 0; r < 4; ++r) {
      float hv = 0.f;
      if (HAS_H) {
        int gn = blk * 64 + 16 * w + 4 * lg + r;
        if (gn > NN - 1) gn = NN - 1;
        hv = h_in[gn * 64 + lr + 16 * tc];
      }
      hmid[tc][r] = fmaf(acc[tc][r], 0.25f, hv);
    }
  ln_frag(hmid);

  __syncthreads();  // all waves past last head phase (bs0/bs1 reads retired)
#pragma unroll
  for (int tc = 0; tc < 4; ++tc)
#pragma unroll
    for (int r = 0; r < 4; ++r) {
      int o = (16 * w + 4 * lg + r) * PITCH + lr + 16 * tc;
      ushort h = f2bf(hmid[tc][r]);
      th[o] = h;
      tl[o] = f2bf(hmid[tc][r] - bf2f(h));
    }
  __syncthreads();
  short8 m0h = *(const short8*)(th + abase);
  short8 m1h = *(const short8*)(th + abase + 32);
  short8 m0l = *(const short8*)(tl + abase);
  short8 m1l = *(const short8*)(tl + abase + 32);

  f32x4 f1[4];
#pragma unroll
  for (int tc = 0; tc < 4; ++tc) f1[tc] = (f32x4)0.f;
  __syncthreads();  // m-frag reads done (held in regs) before bs0 restage
  stageB(ff1p, bs0, t);
  __syncthreads();
  mm_mfma_l<4>(m0h, m1h, m0l, m1l, bs0, l, f1);
#pragma unroll
  for (int tc = 0; tc < 4; ++tc) {
    float bv = ff1b[lr + 16 * tc];
#pragma unroll
    for (int r = 0; r < 4; ++r) {
      float v = fmaxf(f1[tc][r] + bv, 0.f);
      int o = (16 * w + 4 * lg + r) * PITCH + lr + 16 * tc;
      ushort h = f2bf(v);
      th[o] = h;
      tl[o] = f2bf(v - bf2f(h));
    }
  }
  __syncthreads();
  short8 g0h = *(const short8*)(th + abase);
  short8 g1h = *(const short8*)(th + abase + 32);
  short8 g0l = *(const short8*)(tl + abase);
  short8 g1l = *(const short8*)(tl + abase + 32);

  f32x4 f2[4];
#pragma unroll
  for (int tc = 0; tc < 4; ++tc) f2[tc] = (f32x4)0.f;
  __syncthreads();
  stageB(ff2p, bs0, t);
  __syncthreads();
  mm_mfma_l<4>(g0h, g1h, g0l, g1l, bs0, l, f2);
  float F2[4][4];
#pragma unroll
  for (int tc = 0; tc < 4; ++tc) {
    float bv = ff2b[lr + 16 * tc];
#pragma unroll
    for (int r = 0; r < 4; ++r) F2[tc][r] = f2[tc][r] + bv + hmid[tc][r];
  }
  ln_frag(F2);

  if (!DO_CLF) {
#pragma unroll
    for (int r = 0; r < 4; ++r) {
      int gn = blk * 64 + 16 * w + 4 * lg + r;
      if (gn < NN) {
        float dv = WSC ? dinv[gn] : 0.f;
#pragma unroll
        for (int tc = 0; tc < 4; ++tc) {
          h_out[gn * 64 + lr + 16 * tc] = F2[tc][r];
          if (WSC) hs_out[gn * 64 + lr + 16 * tc] = F2[tc][r] * dv;
        }
      }
    }
    return;
  }

  // ===== classifier tail =====
  __syncthreads();  // all waves past FF2 mm (bs0 + tile reads retired)
#pragma unroll
  for (int tc = 0; tc < 4; ++tc)
#pragma unroll
    for (int r = 0; r < 4; ++r) {
      int o = (16 * w + 4 * lg + r) * PITCH + lr + 16 * tc;
      ushort h = f2bf(F2[tc][r]);
      th[o] = h;
      tl[o] = f2bf(F2[tc][r] - bf2f(h));
    }
  stageB(c1p, bs0, t);
  __syncthreads();
  short8 p0h = *(const short8*)(th + abase);
  short8 p1h = *(const short8*)(th + abase + 32);
  short8 p0l = *(const short8*)(tl + abase);
  short8 p1l = *(const short8*)(tl + abase + 32);

  f32x4 c1[4];
#pragma unroll
  for (int tc = 0; tc < 4; ++tc) c1[tc] = (f32x4)0.f;
  mm_mfma_l<4>(p0h, p1h, p0l, p1l, bs0, l, c1);
  __syncthreads();  // bs0 + tile reads retired before overwrite
#pragma unroll
  for (int tc = 0; tc < 4; ++tc) {
    float bv = c1b[lr + 16 * tc];
#pragma unroll
    for (int r = 0; r < 4; ++r) {
      float v = fmaxf(c1[tc][r] + bv, 0.f);
      int o = (16 * w + 4 * lg + r) * PITCH + lr + 16 * tc;
      ushort hh = f2bf(v);
      th[o] = hh;
      tl[o] = f2bf(v - bf2f(hh));
    }
  }
  stageB(c2p, bs0, t);
  __syncthreads();
  short8 q0h = *(const short8*)(th + abase);
  short8 q1h = *(const short8*)(th + abase + 32);
  short8 q0l = *(const short8*)(tl + abase);
  short8 q1l = *(const short8*)(tl + abase + 32);

  f32x4 c2[3];
#pragma unroll
  for (int tc = 0; tc < 3; ++tc) c2[tc] = (f32x4)0.f;
  mm_mfma_l<3>(q0h, q1h, q0l, q1l, bs0, l, c2);
#pragma unroll
  for (int tc = 0; tc < 3; ++tc) {
    int cc = lr + 16 * tc;
    if (cc < 40) {
      float bv = c2b[cc];
#pragma unroll
      for (int r = 0; r < 4; ++r) {
        int gn = blk * 64 + 16 * w + 4 * lg + r;
        if (gn < NN) outv[gn * 40 + cc] = c2[tc][r] + bv;
      }
    }
  }
}

// ---------------- launch ----------------

extern "C" void kernel_launch(void* const* d_in, const int* in_sizes, int n_in,
                              void* d_out, int out_size, void* d_ws, size_t ws_size,
                              hipStream_t stream) {
  (void)in_sizes; (void)n_in; (void)out_size; (void)ws_size;
  const float* x    = (const float*)d_in[0];
  const int*   ei   = (const int*)d_in[1];
  const float* Wh   = (const float*)d_in[2];
  const float* bh   = (const float*)d_in[3];
  const float* Wx   = (const float*)d_in[4];
  const float* bx   = (const float*)d_in[5];
  const float* gfw  = (const float*)d_in[6];
  const float* gfb  = (const float*)d_in[7];
  const float* guw  = (const float*)d_in[8];
  const float* gub  = (const float*)d_in[9];
  const float* ff1w = (const float*)d_in[10];
  const float* ff1b = (const float*)d_in[11];
  const float* ff2w = (const float*)d_in[12];
  const float* ff2b = (const float*)d_in[13];
  const float* c1w  = (const float*)d_in[14];
  const float* c1b  = (const float*)d_in[15];
  const float* c2w  = (const float*)d_in[16];
  const float* c2b  = (const float*)d_in[17];
  float* outv = (float*)d_out;

  char* ws = (char*)d_ws;
  size_t o = 0;
  auto take = [&](size_t b) { char* p = ws + o; o += (b + 255) & ~(size_t)255; return p; };
  int*    deg  = (int*)take((size_t)NN * 4);
  int*    rank = (int*)take((size_t)EE * 4);
  int*    rowp = (int*)take((size_t)(NN + 1) * 4);
  int*    bsum = (int*)take(512 * 4);
  int*    col  = (int*)take((size_t)EE * 4);
  float*  dinv = (float*)take((size_t)NN * 4);
  ushort* wpk  = (ushort*)take((size_t)22 * 8192 * 2);
  ushort* aggXP = (ushort*)take((size_t)NN * 128 * 2);
  ushort* aggHP = (ushort*)take((size_t)NN * 128 * 2);
  float*  hbuf = (float*)take((size_t)NN * 64 * 4);
  float*  xsc  = (float*)take((size_t)NN * 64 * 4);

  const int* srcv = ei;
  const int* dstv = ei + EE;

  const int NB_E = (EE + 255) / 256;
  const int NB_N = (NN + 255) / 256;
  const int NB_V4 = (NN * 16 + 255) / 256;

  k_packz<<<NB_N, 256, 0, stream>>>(Wh, Wx, ff1w, ff2w, c1w, c2w, wpk, deg);
  k_countrank<<<NB_E, 256, 0, stream>>>(dstv, deg, rank);
  k_scan1<<<NB_N, 256, 0, stream>>>(deg, rowp, bsum, dinv);
  k_scan2<<<1, 512, 0, stream>>>(bsum, rowp, NB_N);
  k_scan3<<<NB_N, 256, 0, stream>>>(rowp, bsum);

  // fused: col fill + x prescale (both ready after scan3/scan1)
  k_fillpre<<<NB_E + NB_V4, 256, 0, stream>>>(srcv, dstv, rowp, rank, col, x, dinv, xsc);

  k_spmm<<<(NN + 15) / 16, 256, 0, stream>>>((const float4*)xsc, dinv, rowp, col, aggXP);

  const int NB_L = (NN + 63) / 64;
  // layer 0 (h=0); writes h1 (hbuf) and h1*dinv (xsc)
  k_layer<0, 1, 0><<<NB_L, 256, 0, stream>>>(
      aggXP, aggXP, hbuf, hbuf, xsc, dinv,
      wpk + 0 * 8192, wpk + 8 * 8192, bx, bh, gfw, gfb, guw, gub,
      wpk + 16 * 8192, ff1b, wpk + 18 * 8192, ff2b,
      wpk + 20 * 8192, c1b, wpk + 21 * 8192, c2b, outv);

  k_spmm<<<(NN + 15) / 16, 256, 0, stream>>>((const float4*)xsc, dinv, rowp, col, aggHP);

  // layer 1 + fused classifier -> outv
  k_layer<1, 0, 1><<<NB_L, 256, 0, stream>>>(
      aggXP, aggHP, hbuf, hbuf, xsc, dinv,
      wpk + 4 * 8192, wpk + 12 * 8192, bx + 256, bh + 256, gfw, gfb, guw, gub,
      wpk + 17 * 8192, ff1b + 64, wpk + 19 * 8192, ff2b + 64,
      wpk + 20 * 8192, c1b, wpk + 21 * 8192, c2b, outv);
}

// Round 21
// 331.552 us; speedup vs baseline: 1.1059x; 1.0075x over previous
//
#include <hip/hip_runtime.h>

#define NN 100000
#define EE 1200000
#define ALPHA_C 0.2f
#define EPS_C 1e-5f

typedef __attribute__((ext_vector_type(8))) short short8;
typedef __attribute__((ext_vector_type(4))) float f32x4;
#define MFMA __builtin_amdgcn_mfma_f32_16x16x32_bf16

#define PITCH 72  // LDS tile pitch (ushorts): 144B rows, 16B-aligned frags

// ---------------- bf16 helpers ----------------

__device__ __forceinline__ ushort f2bf(float f) {
  unsigned u = __float_as_uint(f);
  unsigned r = (u + 0x7FFFu + ((u >> 16) & 1u)) >> 16;
  return (ushort)r;
}
__device__ __forceinline__ float bf2f(ushort h) { return __uint_as_float((unsigned)h << 16); }

__device__ __forceinline__ float ftanh(float x) {  // validated (rounds 8/11/12/16/19/20 pass)
  float ax = fabsf(x);
  float e = __expf(2.f * ax);
  float t = 1.f - 2.f / (e + 1.f);
  return copysignf(t, x);
}

// ---------------- CSR build ----------------

__global__ __launch_bounds__(256) void k_countrank(const int* __restrict__ dstv,
                                                   int* __restrict__ deg, int* __restrict__ rank) {
  int e = blockIdx.x * 256 + threadIdx.x;
  if (e < EE) rank[e] = atomicAdd(&deg[dstv[e]], 1);
}

__global__ __launch_bounds__(256) void k_scan1(const int* __restrict__ deg, int* __restrict__ rowp,
                                               int* __restrict__ bsum, float* __restrict__ dinv) {
  __shared__ int s[256];
  int t = threadIdx.x;
  int i = blockIdx.x * 256 + t;
  int v = (i < NN) ? deg[i] : 0;
  if (i < NN) dinv[i] = rsqrtf((float)v + 1.0f);  // +1 self-loop
  s[t] = v;
  __syncthreads();
  for (int off = 1; off < 256; off <<= 1) {
    int add = (t >= off) ? s[t - off] : 0;
    __syncthreads();
    s[t] += add;
    __syncthreads();
  }
  if (i < NN) rowp[i] = s[t] - v;
  if (t == 255) bsum[blockIdx.x] = s[255];
}

__global__ __launch_bounds__(512) void k_scan2(int* __restrict__ bsum, int* __restrict__ rowp, int nb) {
  __shared__ int s[512];
  int t = threadIdx.x;
  int v = (t < nb) ? bsum[t] : 0;
  s[t] = v;
  __syncthreads();
  for (int off = 1; off < 512; off <<= 1) {
    int add = (t >= off) ? s[t - off] : 0;
    __syncthreads();
    s[t] += add;
    __syncthreads();
  }
  if (t < nb) bsum[t] = s[t] - v;
  if (t == 0) rowp[NN] = EE;
}

__global__ __launch_bounds__(256) void k_scan3(int* __restrict__ rowp, const int* __restrict__ bsum) {
  int i = blockIdx.x * 256 + threadIdx.x;
  if (i < NN) rowp[i] += bsum[blockIdx.x];
}

// fused: blocks [0, NB_E) fill col via precomputed rank; blocks [NB_E, ..) prescale x by dinv
#define NB_E_C ((EE + 255) / 256)
__global__ __launch_bounds__(256) void k_fillpre(const int* __restrict__ srcv, const int* __restrict__ dstv,
                                                 const int* __restrict__ rowp, const int* __restrict__ rank,
                                                 int* __restrict__ col,
                                                 const float* __restrict__ feat, const float* __restrict__ dinv,
                                                 float* __restrict__ xs) {
  int b = blockIdx.x;
  if (b < NB_E_C) {
    int e = b * 256 + threadIdx.x;
    if (e < EE) col[rowp[dstv[e]] + rank[e]] = srcv[e];
  } else {
    int idx = (b - NB_E_C) * 256 + threadIdx.x;
    if (idx < NN * 16) {
      float4 v = ((const float4*)feat)[idx];
      float d = dinv[idx >> 4];
      v.x *= d; v.y *= d; v.z *= d; v.w *= d;
      ((float4*)xs)[idx] = v;
    }
  }
}

// ---------------- SpMM ----------------
// out: packed bf16 hi||lo A-fragment layout, 128 ushorts/node ([64 hi][64 lo])
__global__ __launch_bounds__(256) void k_spmm(const float4* __restrict__ xs4, const float* __restrict__ dinv,
                                              const int* __restrict__ rowp, const int* __restrict__ col,
                                              ushort* __restrict__ outP) {
  int node = blockIdx.x * 16 + (threadIdx.x >> 4);
  int q = threadIdx.x & 15;
  if (node >= NN) return;
  int s = rowp[node], e = rowp[node + 1];
  float4 a0 = {0.f, 0.f, 0.f, 0.f}, a1 = a0, a2 = a0, a3 = a0;
  float4 a4 = a0, a5 = a0, a6 = a0, a7 = a0;
  int j = s;
  for (; j + 8 <= e; j += 8) {
    int c0 = col[j],     c1 = col[j + 1], c2 = col[j + 2], c3 = col[j + 3];
    int c4 = col[j + 4], c5 = col[j + 5], c6 = col[j + 6], c7 = col[j + 7];
    float4 v0 = xs4[c0 * 16 + q];
    float4 v1 = xs4[c1 * 16 + q];
    float4 v2 = xs4[c2 * 16 + q];
    float4 v3 = xs4[c3 * 16 + q];
    float4 v4 = xs4[c4 * 16 + q];
    float4 v5 = xs4[c5 * 16 + q];
    float4 v6 = xs4[c6 * 16 + q];
    float4 v7 = xs4[c7 * 16 + q];
    a0 += v0; a1 += v1; a2 += v2; a3 += v3;
    a4 += v4; a5 += v5; a6 += v6; a7 += v7;
  }
  for (; j + 4 <= e; j += 4) {
    int c0 = col[j], c1 = col[j + 1], c2 = col[j + 2], c3 = col[j + 3];
    float4 v0 = xs4[c0 * 16 + q];
    float4 v1 = xs4[c1 * 16 + q];
    float4 v2 = xs4[c2 * 16 + q];
    float4 v3 = xs4[c3 * 16 + q];
    a0 += v0; a1 += v1; a2 += v2; a3 += v3;
  }
  for (; j < e; ++j) a0 += xs4[col[j] * 16 + q];
  float4 sv = xs4[node * 16 + q];
  float d = dinv[node];
  a0 += a4; a1 += a5; a2 += a6; a3 += a7;
  float4 o;
  o.x = d * (a0.x + a1.x + a2.x + a3.x + sv.x);
  o.y = d * (a0.y + a1.y + a2.y + a3.y + sv.y);
  o.z = d * (a0.z + a1.z + a2.z + a3.z + sv.z);
  o.w = d * (a0.w + a1.w + a2.w + a3.w + sv.w);
  ushort h0 = f2bf(o.x), h1 = f2bf(o.y), h2 = f2bf(o.z), h3 = f2bf(o.w);
  ushort l0 = f2bf(o.x - bf2f(h0)), l1 = f2bf(o.y - bf2f(h1)),
         l2 = f2bf(o.z - bf2f(h2)), l3 = f2bf(o.w - bf2f(h3));
  ushort* p = outP + (size_t)node * 128 + 4 * q;
  *(ushort4*)(p) = make_ushort4(h0, h1, h2, h3);
  *(ushort4*)(p + 64) = make_ushort4(l0, l1, l2, l3);
}

// ---------------- weight pre-pack (B-fragment order, hi||lo bf16) + deg zero ----------

__global__ __launch_bounds__(256) void k_packz(const float* __restrict__ Wh, const float* __restrict__ Wx,
                                               const float* __restrict__ ff1w, const float* __restrict__ ff2w,
                                               const float* __restrict__ c1w, const float* __restrict__ c2w,
                                               ushort* __restrict__ wpk, int* __restrict__ deg) {
  int i = blockIdx.x * 256 + threadIdx.x;
  if (i < NN) deg[i] = 0;
  int id = blockIdx.x;
  if (id >= 22) return;
  const float* src;
  int ncol = 64, vcol = 64;
  if (id < 8) src = Wx + id * 4096;
  else if (id < 16) src = Wh + (id - 8) * 4096;
  else if (id < 18) src = ff1w + (id - 16) * 4096;
  else if (id < 20) src = ff2w + (id - 18) * 4096;
  else if (id == 20) src = c1w;
  else { src = c2w; ncol = 40; vcol = 40; }
  ushort* dst = wpk + (size_t)id * 8192;
  for (int p = threadIdx.x; p < 512; p += 256) {
    int f = p >> 6, l = p & 63;
    int kh = f & 1, tc = f >> 1;
    int r0 = 32 * kh + 8 * (l >> 4), c = 16 * tc + (l & 15);
#pragma unroll
    for (int j = 0; j < 8; ++j) {
      float v = (c < vcol) ? src[(r0 + j) * ncol + c] : 0.f;
      ushort h = f2bf(v);
      dst[f * 512 + l * 8 + j] = h;
      dst[4096 + f * 512 + l * 8 + j] = f2bf(v - bf2f(h));
    }
  }
}

// ---------------- dense helpers ----------------

__device__ __forceinline__ float red16(float v) {
  v += __shfl_xor(v, 1);
  v += __shfl_xor(v, 2);
  v += __shfl_xor(v, 4);
  v += __shfl_xor(v, 8);
  return v;
}

__device__ __forceinline__ void stageB(const ushort* __restrict__ wp, ushort* __restrict__ bsta, int t) {
#pragma unroll
  for (int u = 0; u < 4; ++u) {
    int o = (u * 256 + t) * 8;
    *(short8*)(bsta + o) = *(const short8*)(wp + o);
  }
}

template <int NT>
__device__ __forceinline__ void mm_mfma_l(short8 a0h, short8 a1h, short8 a0l, short8 a1l,
                                          const ushort* __restrict__ bsta, int l, f32x4* C) {
#pragma unroll
  for (int tc = 0; tc < NT; ++tc) {
#pragma unroll
    for (int kh = 0; kh < 2; ++kh) {
      const short8 bh = *(const short8*)(bsta + (tc * 2 + kh) * 512 + l * 8);
      const short8 bl = *(const short8*)(bsta + 4096 + (tc * 2 + kh) * 512 + l * 8);
      const short8 ah = kh ? a1h : a0h;
      const short8 alo = kh ? a1l : a0l;
      C[tc] = MFMA(ah, bh, C[tc], 0, 0, 0);
      C[tc] = MFMA(ah, bl, C[tc], 0, 0, 0);
      C[tc] = MFMA(alo, bh, C[tc], 0, 0, 0);
    }
  }
}

__device__ __forceinline__ void ln_frag(float v[4][4]) {
#pragma unroll
  for (int r = 0; r < 4; ++r) {
    float s = v[0][r] + v[1][r] + v[2][r] + v[3][r];
    s = red16(s);
    float mu = s * 0.015625f;
    float q = 0.f;
#pragma unroll
    for (int tc = 0; tc < 4; ++tc) { float d = v[tc][r] - mu; q = fmaf(d, d, q); }
    q = red16(q);
    float inv = rsqrtf(q * 0.015625f + EPS_C);
#pragma unroll
    for (int tc = 0; tc < 4; ++tc) v[tc][r] = (v[tc][r] - mu) * inv;
  }
}

// ---------------- fused per-layer kernel ----------------
// r16/r19 proven structure; this round: FF1/FF2 co-staged into bs0/bs1 at the post-head
// barrier (overlapped with hmid tile write), c1/c2 co-staged at the F2 write. Every tile
// overwrite remains fenced by a full __syncthreads from its prior readers.
// C/D frag: row = 16w + 4*(l>>4) + r, col = (l&15) + 16*tc.

template <int HAS_H, int WSC, int DO_CLF>
__global__ __launch_bounds__(256) void k_layer(
    const ushort* __restrict__ aggXP, const ushort* __restrict__ aggHP,
    const float* __restrict__ h_in, float* __restrict__ h_out,
    float* __restrict__ hs_out, const float* __restrict__ dinv,
    const ushort* __restrict__ wxp, const ushort* __restrict__ whp,
    const float* __restrict__ bxl, const float* __restrict__ bhl,
    const float* __restrict__ gfw, const float* __restrict__ gfb,
    const float* __restrict__ guw, const float* __restrict__ gub,
    const ushort* __restrict__ ff1p, const float* __restrict__ ff1b,
    const ushort* __restrict__ ff2p, const float* __restrict__ ff2b,
    const ushort* __restrict__ c1p, const float* __restrict__ c1b,
    const ushort* __restrict__ c2p, const float* __restrict__ c2b,
    float* __restrict__ outv) {
  __shared__ __align__(16) ushort th[64 * PITCH], tl[64 * PITCH];
  __shared__ __align__(16) ushort bs0[8192], bs1[8192];
  const int t = threadIdx.x, blk = blockIdx.x;
  const int w = t >> 6, l = t & 63, lg = l >> 4, lr = l & 15;
  const int abase = (16 * w + lr) * PITCH + 8 * lg;
  const int arow = blk * 64 + 16 * w + lr;
  const int arowc = arow < NN ? arow : NN - 1;

  const ushort* axp = aggXP + (size_t)arowc * 128 + 8 * lg;
  short8 xa0h = *(const short8*)(axp);
  short8 xa1h = *(const short8*)(axp + 32);
  short8 xa0l = *(const short8*)(axp + 64);
  short8 xa1l = *(const short8*)(axp + 96);
  short8 ha0h = (short8)0, ha1h = (short8)0, ha0l = (short8)0, ha1l = (short8)0;
  if (HAS_H) {
    const ushort* ahp = aggHP + (size_t)arowc * 128 + 8 * lg;
    ha0h = *(const short8*)(ahp);
    ha1h = *(const short8*)(ahp + 32);
    ha0l = *(const short8*)(ahp + 64);
    ha1l = *(const short8*)(ahp + 96);
  }

  float gfhw[4], gfxw[4], guhw[4], guxw[4];
#pragma unroll
  for (int tc = 0; tc < 4; ++tc) {
    gfhw[tc] = gfw[lr + 16 * tc]; gfxw[tc] = gfw[64 + lr + 16 * tc];
    guhw[tc] = guw[lr + 16 * tc]; guxw[tc] = guw[64 + lr + 16 * tc];
  }
  const float gfb0 = gfb[0], gub0 = gub[0];

  float acc[4][4];
#pragma unroll
  for (int tc = 0; tc < 4; ++tc)
#pragma unroll
    for (int r = 0; r < 4; ++r) acc[tc][r] = 0.f;

  // ---- head loop: dual-buffer stage, 2 barriers per head (runtime loop — proven) ----
  for (int k = 0; k < 4; ++k) {
    f32x4 cx[4], ch[4];
#pragma unroll
    for (int tc = 0; tc < 4; ++tc) { cx[tc] = (f32x4)0.f; ch[tc] = (f32x4)0.f; }
    __syncthreads();  // prior readers of bs0/bs1 done
    stageB(wxp + k * 8192, bs0, t);
    if (HAS_H) stageB(whp + k * 8192, bs1, t);
    __syncthreads();  // staged
    mm_mfma_l<4>(xa0h, xa1h, xa0l, xa1l, bs0, l, cx);
    if (HAS_H) mm_mfma_l<4>(ha0h, ha1h, ha0l, ha1l, bs1, l, ch);

    float Cx[4][4], Ch[4][4];
#pragma unroll
    for (int tc = 0; tc < 4; ++tc) {
      float bxv = bxl[k * 64 + lr + 16 * tc];
      float bhv = bhl[k * 64 + lr + 16 * tc];
#pragma unroll
      for (int r = 0; r < 4; ++r) {
        Cx[tc][r] = cx[tc][r] + bxv;
        Ch[tc][r] = (HAS_H ? ch[tc][r] : 0.f) + bhv;
      }
    }
#pragma unroll
    for (int r = 0; r < 4; ++r) {
      float pf = 0.f, pu = 0.f;
#pragma unroll
      for (int tc = 0; tc < 4; ++tc) {
        pf = fmaf(Ch[tc][r], gfhw[tc], pf); pf = fmaf(Cx[tc][r], gfxw[tc], pf);
        pu = fmaf(Ch[tc][r], guhw[tc], pu); pu = fmaf(Cx[tc][r], guxw[tc], pu);
      }
      pf = red16(pf); pu = red16(pu);
      float fv = ALPHA_C * ftanh(pf + gfb0);
      float uv = ALPHA_C * ftanh(pu + gub0);
#pragma unroll
      for (int tc = 0; tc < 4; ++tc)
        acc[tc][r] += (1.f + fv) * Ch[tc][r] + (1.f + uv) * Cx[tc][r];
    }
  }

  // hmid = acc/4 + h_in ; LN
  float hmid[4][4];
#pragma unroll
  for (int tc = 0; tc < 4; ++tc)
#pragma unroll
    for (int r = 0; r < 4; ++r) {
      float hv = 0.f;
      if (HAS_H) {
        int gn = blk * 64 + 16 * w + 4 * lg + r;
        if (gn > NN - 1) gn = NN - 1;
        hv = h_in[gn * 64 + lr + 16 * tc];
      }
      hmid[tc][r] = fmaf(acc[tc][r], 0.25f, hv);
    }
  ln_frag(hmid);

  __syncthreads();  // all waves past last head phase (bs0/bs1 reads retired)
  stageB(ff1p, bs0, t);   // co-stage FF1+FF2 into free buffers
  stageB(ff2p, bs1, t);
#pragma unroll
  for (int tc = 0; tc < 4; ++tc)
#pragma unroll
    for (int r = 0; r < 4; ++r) {
      int o = (16 * w + 4 * lg + r) * PITCH + lr + 16 * tc;
      ushort h = f2bf(hmid[tc][r]);
      th[o] = h;
      tl[o] = f2bf(hmid[tc][r] - bf2f(h));
    }
  __syncthreads();  // hmid tiles visible; FF1/FF2 staged
  short8 m0h = *(const short8*)(th + abase);
  short8 m1h = *(const short8*)(th + abase + 32);
  short8 m0l = *(const short8*)(tl + abase);
  short8 m1l = *(const short8*)(tl + abase + 32);

  f32x4 f1[4];
#pragma unroll
  for (int tc = 0; tc < 4; ++tc) f1[tc] = (f32x4)0.f;
  mm_mfma_l<4>(m0h, m1h, m0l, m1l, bs0, l, f1);
  float F1[4][4];
#pragma unroll
  for (int tc = 0; tc < 4; ++tc) {
    float bv = ff1b[lr + 16 * tc];
#pragma unroll
    for (int r = 0; r < 4; ++r) F1[tc][r] = fmaxf(f1[tc][r] + bv, 0.f);
  }
  __syncthreads();  // all waves' m-frag reads done before tile overwrite
#pragma unroll
  for (int tc = 0; tc < 4; ++tc)
#pragma unroll
    for (int r = 0; r < 4; ++r) {
      int o = (16 * w + 4 * lg + r) * PITCH + lr + 16 * tc;
      ushort h = f2bf(F1[tc][r]);
      th[o] = h;
      tl[o] = f2bf(F1[tc][r] - bf2f(h));
    }
  __syncthreads();  // F1 tiles visible
  short8 g0h = *(const short8*)(th + abase);
  short8 g1h = *(const short8*)(th + abase + 32);
  short8 g0l = *(const short8*)(tl + abase);
  short8 g1l = *(const short8*)(tl + abase + 32);

  f32x4 f2[4];
#pragma unroll
  for (int tc = 0; tc < 4; ++tc) f2[tc] = (f32x4)0.f;
  mm_mfma_l<4>(g0h, g1h, g0l, g1l, bs1, l, f2);
  float F2[4][4];
#pragma unroll
  for (int tc = 0; tc < 4; ++tc) {
    float bv = ff2b[lr + 16 * tc];
#pragma unroll
    for (int r = 0; r < 4; ++r) F2[tc][r] = f2[tc][r] + bv + hmid[tc][r];
  }
  ln_frag(F2);

  if (!DO_CLF) {
#pragma unroll
    for (int r = 0; r < 4; ++r) {
      int gn = blk * 64 + 16 * w + 4 * lg + r;
      if (gn < NN) {
        float dv = WSC ? dinv[gn] : 0.f;
#pragma unroll
        for (int tc = 0; tc < 4; ++tc) {
          h_out[gn * 64 + lr + 16 * tc] = F2[tc][r];
          if (WSC) hs_out[gn * 64 + lr + 16 * tc] = F2[tc][r] * dv;
        }
      }
    }
    return;
  }

  // ===== classifier tail (c1/c2 co-staged) =====
  __syncthreads();  // g-frag reads + FF2 bs1 reads retired
#pragma unroll
  for (int tc = 0; tc < 4; ++tc)
#pragma unroll
    for (int r = 0; r < 4; ++r) {
      int o = (16 * w + 4 * lg + r) * PITCH + lr + 16 * tc;
      ushort h = f2bf(F2[tc][r]);
      th[o] = h;
      tl[o] = f2bf(F2[tc][r] - bf2f(h));
    }
  stageB(c1p, bs0, t);
  stageB(c2p, bs1, t);
  __syncthreads();  // F2 tiles visible; c1/c2 staged
  short8 p0h = *(const short8*)(th + abase);
  short8 p1h = *(const short8*)(th + abase + 32);
  short8 p0l = *(const short8*)(tl + abase);
  short8 p1l = *(const short8*)(tl + abase + 32);

  f32x4 c1[4];
#pragma unroll
  for (int tc = 0; tc < 4; ++tc) c1[tc] = (f32x4)0.f;
  mm_mfma_l<4>(p0h, p1h, p0l, p1l, bs0, l, c1);
  __syncthreads();  // p-frag reads done before tile overwrite
#pragma unroll
  for (int tc = 0; tc < 4; ++tc) {
    float bv = c1b[lr + 16 * tc];
#pragma unroll
    for (int r = 0; r < 4; ++r) {
      float v = fmaxf(c1[tc][r] + bv, 0.f);
      int o = (16 * w + 4 * lg + r) * PITCH + lr + 16 * tc;
      ushort hh = f2bf(v);
      th[o] = hh;
      tl[o] = f2bf(v - bf2f(hh));
    }
  }
  __syncthreads();  // relu(c1) tiles visible
  short8 q0h = *(const short8*)(th + abase);
  short8 q1h = *(const short8*)(th + abase + 32);
  short8 q0l = *(const short8*)(tl + abase);
  short8 q1l = *(const short8*)(tl + abase + 32);

  f32x4 c2[3];
#pragma unroll
  for (int tc = 0; tc < 3; ++tc) c2[tc] = (f32x4)0.f;
  mm_mfma_l<3>(q0h, q1h, q0l, q1l, bs1, l, c2);
#pragma unroll
  for (int tc = 0; tc < 3; ++tc) {
    int cc = lr + 16 * tc;
    if (cc < 40) {
      float bv = c2b[cc];
#pragma unroll
      for (int r = 0; r < 4; ++r) {
        int gn = blk * 64 + 16 * w + 4 * lg + r;
        if (gn < NN) outv[gn * 40 + cc] = c2[tc][r] + bv;
      }
    }
  }
}

// ---------------- launch ----------------

extern "C" void kernel_launch(void* const* d_in, const int* in_sizes, int n_in,
                              void* d_out, int out_size, void* d_ws, size_t ws_size,
                              hipStream_t stream) {
  (void)in_sizes; (void)n_in; (void)out_size; (void)ws_size;
  const float* x    = (const float*)d_in[0];
  const int*   ei   = (const int*)d_in[1];
  const float* Wh   = (const float*)d_in[2];
  const float* bh   = (const float*)d_in[3];
  const float* Wx   = (const float*)d_in[4];
  const float* bx   = (const float*)d_in[5];
  const float* gfw  = (const float*)d_in[6];
  const float* gfb  = (const float*)d_in[7];
  const float* guw  = (const float*)d_in[8];
  const float* gub  = (const float*)d_in[9];
  const float* ff1w = (const float*)d_in[10];
  const float* ff1b = (const float*)d_in[11];
  const float* ff2w = (const float*)d_in[12];
  const float* ff2b = (const float*)d_in[13];
  const float* c1w  = (const float*)d_in[14];
  const float* c1b  = (const float*)d_in[15];
  const float* c2w  = (const float*)d_in[16];
  const float* c2b  = (const float*)d_in[17];
  float* outv = (float*)d_out;

  char* ws = (char*)d_ws;
  size_t o = 0;
  auto take = [&](size_t b) { char* p = ws + o; o += (b + 255) & ~(size_t)255; return p; };
  int*    deg  = (int*)take((size_t)NN * 4);
  int*    rank = (int*)take((size_t)EE * 4);
  int*    rowp = (int*)take((size_t)(NN + 1) * 4);
  int*    bsum = (int*)take(512 * 4);
  int*    col  = (int*)take((size_t)EE * 4);
  float*  dinv = (float*)take((size_t)NN * 4);
  ushort* wpk  = (ushort*)take((size_t)22 * 8192 * 2);
  ushort* aggXP = (ushort*)take((size_t)NN * 128 * 2);
  ushort* aggHP = (ushort*)take((size_t)NN * 128 * 2);
  float*  hbuf = (float*)take((size_t)NN * 64 * 4);
  float*  xsc  = (float*)take((size_t)NN * 64 * 4);

  const int* srcv = ei;
  const int* dstv = ei + EE;

  const int NB_E = (EE + 255) / 256;
  const int NB_N = (NN + 255) / 256;
  const int NB_V4 = (NN * 16 + 255) / 256;

  k_packz<<<NB_N, 256, 0, stream>>>(Wh, Wx, ff1w, ff2w, c1w, c2w, wpk, deg);
  k_countrank<<<NB_E, 256, 0, stream>>>(dstv, deg, rank);
  k_scan1<<<NB_N, 256, 0, stream>>>(deg, rowp, bsum, dinv);
  k_scan2<<<1, 512, 0, stream>>>(bsum, rowp, NB_N);
  k_scan3<<<NB_N, 256, 0, stream>>>(rowp, bsum);

  // fused: col fill + x prescale (both ready after scan3/scan1)
  k_fillpre<<<NB_E + NB_V4, 256, 0, stream>>>(srcv, dstv, rowp, rank, col, x, dinv, xsc);

  k_spmm<<<(NN + 15) / 16, 256, 0, stream>>>((const float4*)xsc, dinv, rowp, col, aggXP);

  const int NB_L = (NN + 63) / 64;
  // layer 0 (h=0); writes h1 (hbuf) and h1*dinv (xsc)
  k_layer<0, 1, 0><<<NB_L, 256, 0, stream>>>(
      aggXP, aggXP, hbuf, hbuf, xsc, dinv,
      wpk + 0 * 8192, wpk + 8 * 8192, bx, bh, gfw, gfb, guw, gub,
      wpk + 16 * 8192, ff1b, wpk + 18 * 8192, ff2b,
      wpk + 20 * 8192, c1b, wpk + 21 * 8192, c2b, outv);

  k_spmm<<<(NN + 15) / 16, 256, 0, stream>>>((const float4*)xsc, dinv, rowp, col, aggHP);

  // layer 1 + fused classifier -> outv
  k_layer<1, 0, 1><<<NB_L, 256, 0, stream>>>(
      aggXP, aggHP, hbuf, hbuf, xsc, dinv,
      wpk + 4 * 8192, wpk + 12 * 8192, bx + 256, bh + 256, gfw, gfb, guw, gub,
      wpk + 17 * 8192, ff1b + 64, wpk + 19 * 8192, ff2b + 64,
      wpk + 20 * 8192, c1b, wpk + 21 * 8192, c2b, outv);
}